// Round 11
// baseline (356.555 us; speedup 1.0000x reference)
//
#include <hip/hip_runtime.h>
#include <hip/hip_bf16.h>

#define D_ 128
#define H_ 8
#define N_ 20000
#define NNZ_ 500000
#define E_ 5000
#define C_ 50
#define NENT_ 50000
#define NK_ (3*N_)
#define CAPE_ 192
#define CAPN_ 64
#define ENT_PB 4096
#define NBKT 157
#define BCAP 3648
#define ABLK 123
#define NCH3 118            // chunks per head, 512 keys each; 1 merged partial per chunk
#define KVBLK 235           // ceil(60000/256)
#define BINA_B (3*ABLK)     // 369 binA blocks, prefixed into prep_binA
#define NBB (3*NBKT)        // 471 binB n-side blocks, prefixed into egather kernel
#define EG2 938             // group-per-edge gather blocks (16 edges/block)

struct Ptr3f { const float* p[3]; };
struct Ptr3i { const int* p[3]; };
struct GemmB { const float* A[3]; const float* W[3]; unsigned short* C[3]; };

typedef short bf16x8 __attribute__((ext_vector_type(8)));
typedef float f32x4  __attribute__((ext_vector_type(4)));
typedef float f32x2  __attribute__((ext_vector_type(2)));

__device__ __forceinline__ unsigned short f2b(float f){
  unsigned u = __float_as_uint(f);
  u += 0x7FFFu + ((u>>16)&1u);
  return (unsigned short)(u>>16);
}
__device__ __forceinline__ unsigned pk2(float a, float b){
  return (unsigned)f2b(a) | ((unsigned)f2b(b) << 16);
}
__device__ __forceinline__ float blo(unsigned u){ return __uint_as_float(u<<16); }
__device__ __forceinline__ float bhi(unsigned u){ return __uint_as_float(u & 0xFFFF0000u); }

// group-gather batch: 8 member rows via group-uniform uint4 slot load; lane dl owns 16B of each row
#define GGATHER8(MB, SLOTP, J) { \
  uint4 sv = *(const uint4*)((SLOTP) + (J)); \
  int o0 = (int)(sv.x & 0xFFFFu) << 8, o1 = (int)(sv.x >> 16) << 8; \
  int o2 = (int)(sv.y & 0xFFFFu) << 8, o3 = (int)(sv.y >> 16) << 8; \
  int o4 = (int)(sv.z & 0xFFFFu) << 8, o5 = (int)(sv.z >> 16) << 8; \
  int o6 = (int)(sv.w & 0xFFFFu) << 8, o7 = (int)(sv.w >> 16) << 8; \
  uint4 u0 = *(const uint4*)((MB) + o0); \
  uint4 u1 = *(const uint4*)((MB) + o1); \
  uint4 u2 = *(const uint4*)((MB) + o2); \
  uint4 u3 = *(const uint4*)((MB) + o3); \
  uint4 u4 = *(const uint4*)((MB) + o4); \
  uint4 u5 = *(const uint4*)((MB) + o5); \
  uint4 u6 = *(const uint4*)((MB) + o6); \
  uint4 u7 = *(const uint4*)((MB) + o7); \
  a01 += (f32x2){blo(u0.x), bhi(u0.x)}; a23 += (f32x2){blo(u0.y), bhi(u0.y)}; \
  a45 += (f32x2){blo(u0.z), bhi(u0.z)}; a67 += (f32x2){blo(u0.w), bhi(u0.w)}; \
  a01 += (f32x2){blo(u1.x), bhi(u1.x)}; a23 += (f32x2){blo(u1.y), bhi(u1.y)}; \
  a45 += (f32x2){blo(u1.z), bhi(u1.z)}; a67 += (f32x2){blo(u1.w), bhi(u1.w)}; \
  a01 += (f32x2){blo(u2.x), bhi(u2.x)}; a23 += (f32x2){blo(u2.y), bhi(u2.y)}; \
  a45 += (f32x2){blo(u2.z), bhi(u2.z)}; a67 += (f32x2){blo(u2.w), bhi(u2.w)}; \
  a01 += (f32x2){blo(u3.x), bhi(u3.x)}; a23 += (f32x2){blo(u3.y), bhi(u3.y)}; \
  a45 += (f32x2){blo(u3.z), bhi(u3.z)}; a67 += (f32x2){blo(u3.w), bhi(u3.w)}; \
  a01 += (f32x2){blo(u4.x), bhi(u4.x)}; a23 += (f32x2){blo(u4.y), bhi(u4.y)}; \
  a45 += (f32x2){blo(u4.z), bhi(u4.z)}; a67 += (f32x2){blo(u4.w), bhi(u4.w)}; \
  a01 += (f32x2){blo(u5.x), bhi(u5.x)}; a23 += (f32x2){blo(u5.y), bhi(u5.y)}; \
  a45 += (f32x2){blo(u5.z), bhi(u5.z)}; a67 += (f32x2){blo(u5.w), bhi(u5.w)}; \
  a01 += (f32x2){blo(u6.x), bhi(u6.x)}; a23 += (f32x2){blo(u6.y), bhi(u6.y)}; \
  a45 += (f32x2){blo(u6.z), bhi(u6.z)}; a67 += (f32x2){blo(u6.w), bhi(u6.w)}; \
  a01 += (f32x2){blo(u7.x), bhi(u7.x)}; a23 += (f32x2){blo(u7.y), bhi(u7.y)}; \
  a45 += (f32x2){blo(u7.z), bhi(u7.z)}; a67 += (f32x2){blo(u7.w), bhi(u7.w)}; \
}

// ---------------- merged prep + binA (independent stages share one launch) ----------------
#define PB_PACK 7500
#define PB_Z    7628
#define PB_Q    7629
#define PB_CTX  7693
#define PB_TOT  7743
__global__ __launch_bounds__(256) void prep_binA(Ptr3f xs, unsigned short* __restrict__ xb,
    const float* __restrict__ Wk, const float* __restrict__ Wv, unsigned short* __restrict__ bfB,
    unsigned short* __restrict__ mzero,
    const float* __restrict__ ctx, const float* __restrict__ Wq, const float* __restrict__ bq,
    unsigned short* __restrict__ bfQ,
    const float* __restrict__ a2, const float* __restrict__ b2, float* __restrict__ e2,
    Ptr3i nodes, Ptr3i edges,
    unsigned* __restrict__ pe_part, unsigned* __restrict__ pn_part,
    int* __restrict__ gcnt_e, int* __restrict__ gcnt_n)
{
  const int t = threadIdx.x;
  if (blockIdx.x < BINA_B){
    // ================= binA =================
    __shared__ unsigned lbin[ENT_PB];
    __shared__ int cnt[256], off[256];
    __shared__ int gbase[NBKT];
    __shared__ int wsum[4];
    const int mod = blockIdx.x / ABLK;
    const int xblk = blockIdx.x - mod*ABLK;
    const int* nd = nodes.p[mod];
    const int* ed = edges.p[mod];
    const int base = xblk * ENT_PB;
    const int lane = t & 63, w = t >> 6;

    int myn[16], mye[16], pos[16];
    #pragma unroll
    for (int k=0;k<16;k++){
      int i = base + t + k*256;
      if (i < NNZ_){ myn[k]=nd[i]; mye[k]=ed[i]; }
      else { myn[k]=-1; mye[k]=-1; }
    }

    cnt[t] = 0;
    __syncthreads();
    #pragma unroll
    for (int k=0;k<16;k++)
      if (mye[k] >= 0) pos[k] = atomicAdd(&cnt[mye[k]>>5], 1);
    __syncthreads();
    {
      int v = cnt[t], s = v;
      #pragma unroll
      for (int d=1; d<64; d<<=1){ int u=__shfl_up(s,d); if (lane>=d) s+=u; }
      if (lane==63) wsum[w]=s;
      __syncthreads();
      int wb=0;
      for (int i=0;i<w;i++) wb+=wsum[i];
      off[t] = wb + s - v;
      __syncthreads();
    }
    #pragma unroll
    for (int k=0;k<16;k++)
      if (mye[k] >= 0)
        lbin[off[mye[k]>>5] + pos[k]] = ((unsigned)mye[k] << 15) | (unsigned)myn[k];
    if (t < NBKT && cnt[t] > 0) gbase[t] = atomicAdd(&gcnt_e[mod*NBKT + t], cnt[t]);
    __syncthreads();
    {
      int total = off[255];
      unsigned* dstreg = pe_part + (size_t)mod*NBKT*BCAP;
      for (int i=t; i<total; i+=256){
        unsigned pk = lbin[i];
        int b = pk >> 20;
        int gp = gbase[b] + (i - off[b]);
        if (gp < BCAP) dstreg[(size_t)b*BCAP + gp] = pk;
      }
    }
    __syncthreads();

    cnt[t] = 0;
    __syncthreads();
    #pragma unroll
    for (int k=0;k<16;k++)
      if (myn[k] >= 0) pos[k] = atomicAdd(&cnt[myn[k]>>7], 1);
    __syncthreads();
    {
      int v = cnt[t], s = v;
      #pragma unroll
      for (int d=1; d<64; d<<=1){ int u=__shfl_up(s,d); if (lane>=d) s+=u; }
      if (lane==63) wsum[w]=s;
      __syncthreads();
      int wb=0;
      for (int i=0;i<w;i++) wb+=wsum[i];
      off[t] = wb + s - v;
      __syncthreads();
    }
    #pragma unroll
    for (int k=0;k<16;k++)
      if (myn[k] >= 0)
        lbin[off[myn[k]>>7] + pos[k]] = ((unsigned)myn[k] << 13) | (unsigned)mye[k];
    if (t < NBKT && cnt[t] > 0) gbase[t] = atomicAdd(&gcnt_n[mod*NBKT + t], cnt[t]);
    __syncthreads();
    {
      int total = off[255];
      unsigned* dstreg = pn_part + (size_t)mod*NBKT*BCAP;
      for (int i=t; i<total; i+=256){
        unsigned pk = lbin[i];
        int b = pk >> 20;
        int gp = gbase[b] + (i - off[b]);
        if (gp < BCAP) dstreg[(size_t)b*BCAP + gp] = pk;
      }
    }
    return;
  }

  // ================= prep =================
  int bid = blockIdx.x - BINA_B;
  if (bid < PB_PACK){
    int mod = bid / 2500, blk = bid - mod*2500;
    int i4 = blk*256 + t;
    float4 v = *(const float4*)(xs.p[mod] + (size_t)i4*4);
    ushort4 o; o.x=f2b(v.x); o.y=f2b(v.y); o.z=f2b(v.z); o.w=f2b(v.w);
    *(ushort4*)(xb + (size_t)mod*N_*D_ + (size_t)i4*4) = o;
  } else if (bid < PB_Z){
    int idx = (bid - PB_PACK)*256 + t;     // 32768
    int j  = idx & 7;
    int L  = (idx >> 3) & 63;
    int kb = (idx >> 9) & 3;
    int tt = idx >> 11;
    int k = kb*32 + (L>>4)*8 + j;
    int x = L & 15;
    float v = (tt < 8) ? Wk[(size_t)k*128 + tt*16 + x] : Wv[(size_t)k*128 + (tt-8)*16 + x];
    bfB[idx] = f2b(v);
  } else if (bid == PB_Z){
    if (t < 64)       ((unsigned*)(xb    + (size_t)60000*128))[t]    = 0u;   // zero gather row (e-side)
    else if (t < 128) ((unsigned*)(mzero + (size_t)15000*128))[t-64] = 0u;   // zero gather row (n-side)
  } else if (bid < PB_CTX){
    int idx = (bid - PB_Q)*256 + t;        // 16384
    int j  = idx & 7;
    int L  = (idx >> 3) & 63;
    int qt = (idx >> 9) & 3;
    int h  = idx >> 11;
    int k  = ((L>>4)&3)*8 + j;
    int q  = qt*16 + (L & 15);
    float val = 0.f;
    if (k < 16 && q < C_){
      const float* cr = ctx + (size_t)q*128;
      const float* wc = Wq + h*16 + k;
      float s0=0.f,s1=0.f,s2=0.f,s3=0.f;
      for (int d=0; d<128; d+=4){
        s0 = fmaf(cr[d],   wc[(size_t) d   *128], s0);
        s1 = fmaf(cr[d+1], wc[(size_t)(d+1)*128], s1);
        s2 = fmaf(cr[d+2], wc[(size_t)(d+2)*128], s2);
        s3 = fmaf(cr[d+3], wc[(size_t)(d+3)*128], s3);
      }
      val = 0.25f * (s0+s1+s2+s3 + bq[h*16+k]);
    }
    bfQ[idx] = f2b(val);
  } else {
    __shared__ float row[128];
    __shared__ float ps[128][2];
    __shared__ float red[2];
    int q = bid - PB_CTX;
    if (t < 128) row[t] = ctx[(size_t)q*128 + t];
    __syncthreads();
    int c = t & 127, half = t >> 7;
    float s = 0.f;
    int d0 = half*64;
    for (int d=d0; d<d0+64; d+=4){
      s = fmaf(row[d],   a2[(size_t) d   *128 + c], s);
      s = fmaf(row[d+1], a2[(size_t)(d+1)*128 + c], s);
      s = fmaf(row[d+2], a2[(size_t)(d+2)*128 + c], s);
      s = fmaf(row[d+3], a2[(size_t)(d+3)*128 + c], s);
    }
    ps[c][half] = s;
    __syncthreads();
    if (t < 128){
      float v = tanhf(ps[t][0] + ps[t][1]) * b2[t];
      #pragma unroll
      for (int k=32; k>=1; k>>=1) v += __shfl_xor(v, k);
      if ((t & 63) == 0) red[t>>6] = v;
    }
    __syncthreads();
    if (t == 0) e2[q] = red[0] + red[1];
  }
}

// ---------------- binB e-side only (dummy-padded slot rows) ----------------
__global__ __launch_bounds__(256) void binB_e(const unsigned* __restrict__ pe_part,
    const int* __restrict__ gcnt_e, int* __restrict__ cnt_all,
    unsigned short* __restrict__ e_slot)
{
  __shared__ unsigned short ls[32*CAPE_];
  __shared__ int lc[32];
  const int mod = blockIdx.y, b = blockIdx.x, t = threadIdx.x;
  {
    unsigned short dmy = (unsigned short)(60000 - mod*20000);
    unsigned dd = (unsigned)dmy * 0x10001u;
    unsigned* lsu32 = (unsigned*)ls;
    for (int i=t; i<32*CAPE_/2; i+=256) lsu32[i] = dd;
  }
  if (t < 32) lc[t] = 0;
  __syncthreads();
  int cnt = gcnt_e[mod*NBKT + b];
  if (cnt > BCAP) cnt = BCAP;
  const unsigned* src = pe_part + ((size_t)mod*NBKT + b)*BCAP;
  for (int i=t; i<cnt; i+=256){
    unsigned pk = src[i];
    int el = (pk >> 15) - b*32;
    int n  = pk & 0x7FFF;
    int p = atomicAdd(&lc[el], 1);
    if (p < CAPE_) ls[el*CAPE_ + p] = (unsigned short)n;
  }
  __syncthreads();
  int rows = E_ - b*32; if (rows > 32) rows = 32;
  if (t < rows) cnt_all[mod*(E_+N_) + b*32 + t] = lc[t];
  const unsigned* lsu = (const unsigned*)ls;
  unsigned* dst = (unsigned*)(e_slot + ((size_t)mod*E_ + b*32)*CAPE_);
  int tot = rows*CAPE_/2;
  for (int i=t; i<tot; i+=256) dst[i] = lsu[i];
}

// ---------------- merged binB n-side + group-per-edge gather ----------------
// blocks [0, NBB): binB n-side; blocks [NBB, NBB+EG2): e_gather (16 edges/block,
// 16-lane group per edge, zero cross-lane ops).
__global__ __launch_bounds__(256) void egather_binbn(const unsigned short* __restrict__ xb,
    const int* __restrict__ cnt_all, const unsigned short* __restrict__ e_slot,
    float* __restrict__ m_mean,
    const unsigned* __restrict__ pn_part, const int* __restrict__ gcnt_n,
    int* __restrict__ cnt_all_w, unsigned short* __restrict__ n_slot)
{
  __shared__ unsigned short ls[128*CAPN_];
  __shared__ int lc[128];
  const int t = threadIdx.x;
  if (blockIdx.x < NBB){
    // ================= binB n-side =================
    const int mod = blockIdx.x / NBKT, b = blockIdx.x - mod*NBKT;
    {
      unsigned short dmy = (unsigned short)(15000 - mod*5000);
      unsigned dd = (unsigned)dmy * 0x10001u;
      unsigned* lsu32 = (unsigned*)ls;
      for (int i=t; i<128*CAPN_/2; i+=256) lsu32[i] = dd;
    }
    if (t < 128) lc[t] = 0;
    __syncthreads();
    int cnt = gcnt_n[mod*NBKT + b];
    if (cnt > BCAP) cnt = BCAP;
    const unsigned* src = pn_part + ((size_t)mod*NBKT + b)*BCAP;
    for (int i=t; i<cnt; i+=256){
      unsigned pk = src[i];
      int nl = (pk >> 13) - b*128;
      int e  = pk & 0x1FFF;
      int p = atomicAdd(&lc[nl], 1);
      if (p < CAPN_) ls[nl*CAPN_ + p] = (unsigned short)e;
    }
    __syncthreads();
    int rows = N_ - b*128; if (rows > 128) rows = 128;
    if (t < rows) cnt_all_w[mod*(E_+N_) + E_ + b*128 + t] = lc[t];
    const unsigned* lsu = (const unsigned*)ls;
    unsigned* dst = (unsigned*)(n_slot + ((size_t)mod*N_ + b*128)*CAPN_);
    int tot = rows*CAPN_/2;
    for (int i=t; i<tot; i+=256) dst[i] = lsu[i];
    return;
  }

  // ================= group-per-edge e_gather =================
  const int bb = blockIdx.x - NBB;
  const int w = t >> 6, lane = t & 63;
  const int g = lane >> 4, dl = lane & 15;
  int eg = bb*16 + w*4 + g;
  if (eg >= 3*E_) return;
  int mod = eg / E_;
  int e = eg - mod*E_;
  const char* mb = (const char*)(xb + (size_t)mod*N_*D_) + dl*16;
  int cnt = cnt_all[mod*(E_+N_) + e];
  int c2 = (cnt < CAPE_) ? cnt : CAPE_;
  int m8 = (c2 + 7) & ~7;                    // <= 192; tail dummy rows add 0
  const unsigned short* slot = e_slot + ((size_t)mod*E_ + e)*CAPE_;
  f32x2 a01={0.f,0.f}, a23={0.f,0.f}, a45={0.f,0.f}, a67={0.f,0.f};

  for (int j=0; j<m8; j+=8) GGATHER8(mb, slot, j)

  float inv = 1.f / fmaxf((float)cnt, 1.f);
  float* dst = m_mean + ((size_t)mod*E_ + e)*128 + dl*8;
  float4 o1; o1.x=a01.x*inv; o1.y=a01.y*inv; o1.z=a23.x*inv; o1.w=a23.y*inv;
  float4 o2; o2.x=a45.x*inv; o2.y=a45.y*inv; o2.z=a67.x*inv; o2.w=a67.y*inv;
  *(float4*)dst = o1;
  *(float4*)(dst + 4) = o2;
}

// ---------------- batched theta GEMM ----------------
__global__ __launch_bounds__(256) void gemm_b(GemmB g, int M)
{
  const float* A = g.A[blockIdx.y];
  const float* W = g.W[blockIdx.y];
  unsigned short* Cout = g.C[blockIdx.y];
  __shared__ float As[64][33];
  __shared__ float Ws[32][128];
  const int t  = threadIdx.x;
  const int br = blockIdx.x * 64;
  const int r0 = (t >> 5) * 8;
  const int c0 = (t & 31) * 4;
  const int lr = t >> 2;
  const int lk = (t & 3) * 8;
  const int wk = t >> 5;

  float acc[8][4];
  #pragma unroll
  for (int i=0;i<8;i++){ acc[i][0]=0.f; acc[i][1]=0.f; acc[i][2]=0.f; acc[i][3]=0.f; }

  for (int kb=0; kb<128; kb+=32){
    float av[8];
    const int grow = br + lr;
    if (grow < M){
      const float* p = A + (size_t)grow*128 + kb + lk;
      float4 a = ((const float4*)p)[0], b = ((const float4*)p)[1];
      av[0]=a.x;av[1]=a.y;av[2]=a.z;av[3]=a.w;av[4]=b.x;av[5]=b.y;av[6]=b.z;av[7]=b.w;
    } else {
      #pragma unroll
      for (int j=0;j<8;j++) av[j]=0.f;
    }
    float4 wv4[4];
    #pragma unroll
    for (int kk=0;kk<4;kk++) wv4[kk] = *(const float4*)&W[(size_t)(kb + wk + kk*8)*128 + c0];

    __syncthreads();
    #pragma unroll
    for (int j=0;j<8;j++) As[lr][lk+j] = av[j];
    #pragma unroll
    for (int kk=0;kk<4;kk++) *(float4*)&Ws[wk + kk*8][c0] = wv4[kk];
    __syncthreads();

    #pragma unroll
    for (int k=0;k<32;k++){
      float4 wv = *(const float4*)&Ws[k][c0];
      #pragma unroll
      for (int i=0;i<8;i++){
        float a = As[r0+i][k];
        acc[i][0] = fmaf(a, wv.x, acc[i][0]);
        acc[i][1] = fmaf(a, wv.y, acc[i][1]);
        acc[i][2] = fmaf(a, wv.z, acc[i][2]);
        acc[i][3] = fmaf(a, wv.w, acc[i][3]);
      }
    }
  }

  #pragma unroll
  for (int i=0;i<8;i++){
    int gr = br + r0 + i;
    if (gr < M){
      ushort4 o;
      o.x=f2b(acc[i][0]); o.y=f2b(acc[i][1]); o.z=f2b(acc[i][2]); o.w=f2b(acc[i][3]);
      *(ushort4*)(Cout + (size_t)gr*128 + c0) = o;
    }
  }
}

// ---------------- group-per-node gather-mean + bias -> bf16 related ----------------
__global__ __launch_bounds__(256) void n_gather_g(const unsigned short* __restrict__ m_buf,
    const int* __restrict__ cnt_all, const unsigned short* __restrict__ n_slot,
    Ptr3f biases, unsigned short* __restrict__ relbf)
{
  const int mod = blockIdx.y;
  const int t = threadIdx.x, w = t >> 6, lane = t & 63;
  const int g = lane >> 4, dl = lane & 15;
  const int n = blockIdx.x*16 + w*4 + g;
  const char* mb = (const char*)(m_buf + (size_t)mod*E_*D_) + dl*16;
  int cnt = cnt_all[mod*(E_+N_) + E_ + n];
  int c2 = (cnt < CAPN_) ? cnt : CAPN_;
  int m8 = (c2 + 7) & ~7;                    // <= 64; tail dummy rows add 0
  const unsigned short* slot = n_slot + ((size_t)mod*N_ + n)*CAPN_;
  f32x2 a01={0.f,0.f}, a23={0.f,0.f}, a45={0.f,0.f}, a67={0.f,0.f};

  for (int j=0; j<m8; j+=8) GGATHER8(mb, slot, j)

  float inv = 1.f / fmaxf((float)cnt, 1.f);
  const float* bs = biases.p[mod] + dl*8;
  uint4 o;
  o.x = pk2(a01.x*inv + bs[0], a01.y*inv + bs[1]);
  o.y = pk2(a23.x*inv + bs[2], a23.y*inv + bs[3]);
  o.z = pk2(a45.x*inv + bs[4], a45.y*inv + bs[5]);
  o.w = pk2(a67.x*inv + bs[6], a67.y*inv + bs[7]);
  *(uint4*)(relbf + ((size_t)mod*N_ + n)*128 + dl*8) = o;
}

// ---------------- MFMA KV GEMM v2: B from L2, V staged in LDS for coalesced writes ----------------
__global__ __launch_bounds__(256) void gemm_kv_mfma(const unsigned short* __restrict__ relbf,
    const unsigned short* __restrict__ bfB, const float* __restrict__ bk,
    const float* __restrict__ bv, unsigned short* __restrict__ Kb,
    unsigned short* __restrict__ Vtg)
{
  __shared__ unsigned short Vs[128][72];   // 18.4 KB, 144B rows (16B-aligned)
  const int t = threadIdx.x, w = t >> 6, L = t & 63;
  const int m = L & 15, quad = L >> 4, x = m;
  const int rowbase = blockIdx.x*256;

  for (int g = 0; g < 4; g++){
    const int j0 = rowbase + g*64 + w*16;

    bf16x8 a[4];
    {
      int row = j0 + m;
      int rowc = (row < NK_) ? row : (NK_-1);
      #pragma unroll
      for (int kb=0; kb<4; kb++)
        a[kb] = *(const bf16x8*)(relbf + (size_t)rowc*128 + kb*32 + quad*8);
    }

    f32x4 acc[16];
    #pragma unroll
    for (int tt=0; tt<16; tt++) acc[tt] = (f32x4){0.f,0.f,0.f,0.f};

    #pragma unroll
    for (int kb=0; kb<4; kb++){
      #pragma unroll
      for (int tt=0; tt<16; tt++){
        bf16x8 b = *(const bf16x8*)(bfB + (((tt*4 + kb)*64 + L) << 3));
        acc[tt] = __builtin_amdgcn_mfma_f32_16x16x32_bf16(a[kb], b, acc[tt], 0, 0, 0);
      }
    }

    // ---- K: direct stores (already 32B-contiguous across x lanes) ----
    #pragma unroll
    for (int tt=0; tt<8; tt++){
      float bias = bk[tt*16 + x];
      unsigned p0, p1;
      asm("v_cvt_pk_bf16_f32 %0, %1, %2" : "=v"(p0) : "v"(acc[tt][0]+bias), "v"(acc[tt][1]+bias));
      asm("v_cvt_pk_bf16_f32 %0, %1, %2" : "=v"(p1) : "v"(acc[tt][2]+bias), "v"(acc[tt][3]+bias));
      int jrb = j0 + quad*4;
      if (jrb + 3 < NK_){
        Kb[(((size_t)tt*NK_ + jrb    ) << 4) + x] = (unsigned short)p0;
        Kb[(((size_t)tt*NK_ + jrb + 1) << 4) + x] = (unsigned short)(p0 >> 16);
        Kb[(((size_t)tt*NK_ + jrb + 2) << 4) + x] = (unsigned short)p1;
        Kb[(((size_t)tt*NK_ + jrb + 3) << 4) + x] = (unsigned short)(p1 >> 16);
      } else {
        if (jrb     < NK_) Kb[(((size_t)tt*NK_ + jrb    ) << 4) + x] = (unsigned short)p0;
        if (jrb + 1 < NK_) Kb[(((size_t)tt*NK_ + jrb + 1) << 4) + x] = (unsigned short)(p0 >> 16);
        if (jrb + 2 < NK_) Kb[(((size_t)tt*NK_ + jrb + 2) << 4) + x] = (unsigned short)p1;
        if (jrb + 3 < NK_) Kb[(((size_t)tt*NK_ + jrb + 3) << 4) + x] = (unsigned short)(p1 >> 16);
      }
    }

    // ---- V: stage to LDS (col-contiguous matches register layout) ----
    #pragma unroll
    for (int tt=8; tt<16; tt++){
      int h = tt - 8;
      float bias = bv[h*16 + x];
      unsigned p0, p1;
      asm("v_cvt_pk_bf16_f32 %0, %1, %2" : "=v"(p0) : "v"(acc[tt][0]+bias), "v"(acc[tt][1]+bias));
      asm("v_cvt_pk_bf16_f32 %0, %1, %2" : "=v"(p1) : "v"(acc[tt][2]+bias), "v"(acc[tt][3]+bias));
      int col = w*16 + quad*4;
      *(unsigned*)&Vs[h*16 + x][col]     = p0;
      *(unsigned*)&Vs[h*16 + x][col + 2] = p1;
    }
    __syncthreads();

    // ---- V flush: 128 rows x 64 cols, 64B contiguous per thread ----
    {
      int row = t >> 1, half = t & 1;
      int c0 = half*32;
      int jr0 = rowbase + g*64 + c0;
      const unsigned short* src = &Vs[row][c0];
      unsigned short* dstp = Vtg + (size_t)row*NK_ + jr0;
      if (jr0 + 31 < NK_){
        ((uint4*)dstp)[0] = ((const uint4*)src)[0];
        ((uint4*)dstp)[1] = ((const uint4*)src)[1];
        ((uint4*)dstp)[2] = ((const uint4*)src)[2];
        ((uint4*)dstp)[3] = ((const uint4*)src)[3];
      } else {
        for (int c=0; c<32; c++) if (jr0 + c < NK_) dstp[c] = src[c];
      }
    }
    __syncthreads();
  }
}

// ---------------- MFMA flash with in-block 4-wave merge (512-key chunks for occupancy) ----------------
__global__ __launch_bounds__(256) void flash3(const unsigned short* __restrict__ Kb,
    const unsigned short* __restrict__ Vtg, const unsigned short* __restrict__ bfQ,
    float* __restrict__ part)
{
  __shared__ unsigned short P_lds[4][64][40];
  __shared__ float mbuf[4][64][18];
  const int c = blockIdx.x, h = blockIdx.y;
  const int t = threadIdx.x, w = t >> 6, L = t & 63;
  const int n = L & 15, quad = L >> 4;

  bf16x8 qb[4];
  #pragma unroll
  for (int qt=0; qt<4; qt++)
    qb[qt] = *(const bf16x8*)(bfQ + (((h*4 + qt)*64 + L) << 3));

  float Mc[4], Lc[4];
  f32x4 accq[4];
  #pragma unroll
  for (int qt=0; qt<4; qt++){ Mc[qt] = -INFINITY; Lc[qt] = 0.f; accq[qt] = (f32x4){0.f,0.f,0.f,0.f}; }

  const int base = c*512 + w*128;
  unsigned* Pw = (unsigned*)&P_lds[w][0][0];

  for (int tile=0; tile<4; tile++){
    const int j0 = base + tile*32;
    const bool dead = (j0 >= NK_);

    bf16x8 a0 = (bf16x8){0,0,0,0,0,0,0,0};
    bf16x8 a1 = a0;
    if (quad < 2){
      int k0 = j0 + n;      if (k0 > NK_-1) k0 = NK_-1;
      int k1 = j0 + 16 + n; if (k1 > NK_-1) k1 = NK_-1;
      a0 = *(const bf16x8*)(Kb + (((size_t)h*NK_ + k0) << 4) + quad*8);
      a1 = *(const bf16x8*)(Kb + (((size_t)h*NK_ + k1) << 4) + quad*8);
    }
    f32x4 s0[4], s1[4];
    #pragma unroll
    for (int qt=0; qt<4; qt++){
      s0[qt] = __builtin_amdgcn_mfma_f32_16x16x32_bf16(a0, qb[qt], (f32x4){0.f,0.f,0.f,0.f}, 0,0,0);
      s1[qt] = __builtin_amdgcn_mfma_f32_16x16x32_bf16(a1, qb[qt], (f32x4){0.f,0.f,0.f,0.f}, 0,0,0);
    }

    #pragma unroll
    for (int qt=0; qt<4; qt++){
      float mt = s0[qt][0];
      mt = fmaxf(mt, s0[qt][1]); mt = fmaxf(mt, s0[qt][2]); mt = fmaxf(mt, s0[qt][3]);
      mt = fmaxf(mt, s1[qt][0]); mt = fmaxf(mt, s1[qt][1]);
      mt = fmaxf(mt, s1[qt][2]); mt = fmaxf(mt, s1[qt][3]);
      mt = fmaxf(mt, __shfl_xor(mt, 16));
      mt = fmaxf(mt, __shfl_xor(mt, 32));
      float Mn = fmaxf(Mc[qt], mt);
      float corr = __expf(Mc[qt] - Mn);
      Mc[qt] = Mn;
      float p0[4], p1[4];
      #pragma unroll
      for (int r=0;r<4;r++){
        p0[r] = __expf(s0[qt][r] - Mn);
        p1[r] = __expf(s1[qt][r] - Mn);
      }
      if (dead){
        #pragma unroll
        for (int r=0;r<4;r++){ p0[r]=0.f; p1[r]=0.f; }
      }
      float lt = p0[0]+p0[1]+p0[2]+p0[3]+p1[0]+p1[1]+p1[2]+p1[3];
      lt += __shfl_xor(lt, 16);
      lt += __shfl_xor(lt, 32);
      Lc[qt] = Lc[qt]*corr + lt;
      int rb = (qt*16 + n)*20;
      Pw[rb + quad*2]     = pk2(p0[0], p0[1]);
      Pw[rb + quad*2 + 1] = pk2(p0[2], p0[3]);
      Pw[rb + 8 + quad*2]     = pk2(p1[0], p1[1]);
      Pw[rb + 8 + quad*2 + 1] = pk2(p1[2], p1[3]);
      #pragma unroll
      for (int r=0;r<4;r++){
        float cr = __shfl(corr, quad*4 + r);
        accq[qt][r] *= cr;
      }
    }
    __syncthreads();

    bf16x8 bv_;
    {
      int va = j0 + quad*8; if (va > NK_-8) va = NK_-8;
      bv_ = *(const bf16x8*)(Vtg + ((size_t)(h*16 + n))*NK_ + va);
    }
    #pragma unroll
    for (int qt=0; qt<4; qt++){
      bf16x8 pa = *(const bf16x8*)&P_lds[w][qt*16 + n][quad*8];
      accq[qt] = __builtin_amdgcn_mfma_f32_16x16x32_bf16(pa, bv_, accq[qt], 0,0,0);
    }
    __syncthreads();
  }

  #pragma unroll
  for (int qt=0; qt<4; qt++){
    #pragma unroll
    for (int r=0; r<4; r++)
      mbuf[w][qt*16 + quad*4 + r][2 + n] = accq[qt][r];
    if (quad == 0){
      mbuf[w][qt*16 + n][0] = Mc[qt];
      mbuf[w][qt*16 + n][1] = Lc[qt];
    }
  }
  __syncthreads();
  if (t < C_){
    float M = mbuf[0][t][0], Lm = mbuf[0][t][1];
    float A[16];
    #pragma unroll
    for (int i=0;i<16;i++) A[i] = mbuf[0][t][2+i];
    #pragma unroll
    for (int ww=1; ww<4; ww++){
      float pm = mbuf[ww][t][0], pl = mbuf[ww][t][1];
      if (pl > 0.f){
        float mn = fmaxf(M, pm);
        float c1 = __expf(M - mn), c2 = __expf(pm - mn);
        Lm = Lm*c1 + pl*c2;
        #pragma unroll
        for (int i=0;i<16;i++) A[i] = A[i]*c1 + mbuf[ww][t][2+i]*c2;
        M = mn;
      }
    }
    float* pp = part + ((size_t)(h*NCH3 + c)*C_ + t)*18;
    pp[0] = M; pp[1] = Lm;
    #pragma unroll
    for (int i=0;i<16;i++) pp[2+i] = A[i];
  }
}

// ---------------- wave-parallel flash-merge + O-projection + e1 row ----------------
__global__ __launch_bounds__(512) void merge_oproj_e1(const float* __restrict__ part,
    const float* __restrict__ Wo, const float* __restrict__ bo,
    const float* __restrict__ a1, const float* __restrict__ b1,
    float* __restrict__ attentive, float* __restrict__ e1)
{
  __shared__ float row[128];
  __shared__ float ps[128][4];
  __shared__ float orow[128];
  __shared__ float red[2];
  const int q = blockIdx.x, t = threadIdx.x;
  const int h = t >> 6, lane = t & 63;

  // ---- stage A: wave h merges NCH3 chunk partials for (h, q) ----
  {
    float M = -1e30f, L = 0.f;
    float A[16];
    #pragma unroll
    for (int i=0;i<16;i++) A[i] = 0.f;

    #pragma unroll
    for (int cc=0; cc<2; cc++){
      int c = lane + cc*64;
      if (c < NCH3){
        const float* p = part + ((size_t)(h*NCH3 + c)*C_ + q)*18;
        float pm = p[0], pl = p[1];
        if (pl > 0.f){
          float Mn = fmaxf(M, pm);
          float w1 = __expf(M - Mn), w2 = __expf(pm - Mn);
          L = L*w1 + pl*w2;
          #pragma unroll
          for (int i=0;i<16;i++) A[i] = fmaf(A[i], w1, p[2+i]*w2);
          M = Mn;
        }
      }
    }
    // 6-round butterfly merge across the wave
    #pragma unroll
    for (int d=32; d>=1; d>>=1){
      float pm = __shfl_xor(M, d);
      float pl = __shfl_xor(L, d);
      float Ao[16];
      #pragma unroll
      for (int i=0;i<16;i++) Ao[i] = __shfl_xor(A[i], d);
      float Mn = fmaxf(M, pm);
      float w1 = __expf(M - Mn), w2 = __expf(pm - Mn);
      L = L*w1 + pl*w2;
      #pragma unroll
      for (int i=0;i<16;i++) A[i] = fmaf(A[i], w1, Ao[i]*w2);
      M = Mn;
    }
    if (lane == 0){
      float invL = 1.f / L;
      #pragma unroll
      for (int i=0;i<16;i++) row[h*16 + i] = A[i]*invL;
    }
  }
  __syncthreads();

  // ---- stage B: O-projection (4-way d-split over 512 threads) ----
  const int c = t & 127, seg = t >> 7;
  {
    float s = 0.f;
    int d0 = seg*32;
    for (int d=d0; d<d0+32; d+=4){
      s = fmaf(row[d],   Wo[(size_t) d   *128 + c], s);
      s = fmaf(row[d+1], Wo[(size_t)(d+1)*128 + c], s);
      s = fmaf(row[d+2], Wo[(size_t)(d+2)*128 + c], s);
      s = fmaf(row[d+3], Wo[(size_t)(d+3)*128 + c], s);
    }
    ps[c][seg] = s;
  }
  __syncthreads();
  if (t < 128){
    float o = ps[t][0]+ps[t][1]+ps[t][2]+ps[t][3] + bo[t];
    attentive[(size_t)q*128 + t] = o;
    orow[t] = o;
  }
  __syncthreads();
  // ---- e1 row: tanh(orow @ a1) @ b1 ----
  {
    float s = 0.f;
    int d0 = seg*32;
    for (int d=d0; d<d0+32; d+=4){
      s = fmaf(orow[d],   a1[(size_t) d   *128 + c], s);
      s = fmaf(orow[d+1], a1[(size_t)(d+1)*128 + c], s);
      s = fmaf(orow[d+2], a1[(size_t)(d+2)*128 + c], s);
      s = fmaf(orow[d+3], a1[(size_t)(d+3)*128 + c], s);
    }
    ps[c][seg] = s;
  }
  __syncthreads();
  if (t < 128){
    float v = tanhf(ps[t][0]+ps[t][1]+ps[t][2]+ps[t][3]) * b1[t];
    #pragma unroll
    for (int k=32; k>=1; k>>=1) v += __shfl_xor(v, k);
    if ((t & 63) == 0) red[t>>6] = v;
  }
  __syncthreads();
  if (t == 0) e1[q] = red[0] + red[1];
}

// ---------------- fused tail + scores ----------------
__global__ __launch_bounds__(256) void tail_scores(const float* __restrict__ attentive,
    const float* __restrict__ ctx, const float* __restrict__ a2, const float* __restrict__ b2,
    const float* __restrict__ e1, const float* __restrict__ e2,
    const float* __restrict__ recW, const float* __restrict__ recb, float* __restrict__ out)
{
  __shared__ float p[64];
  __shared__ float u[128];
  __shared__ float red[2];
  __shared__ float p2[64];
  __shared__ float ur[128];
  const int t = threadIdx.x;

  if (t == 0){
    float mx=-INFINITY;
    for (int i=0;i<C_;i++) mx=fmaxf(mx,e1[i]);
    float ss=0.f;
    for (int i=0;i<C_;i++){ p[i]=__expf(e1[i]-mx); ss+=p[i]; }
    float inv=1.f/ss;
    for (int i=0;i<C_;i++) p[i]*=inv;
  }
  __syncthreads();
  if (t < 128){
    float s=0.f;
    for (int r=0;r<C_;r++) s = fmaf(p[r], attentive[(size_t)r*128 + t], s);
    u[t] = s;
  }
  __syncthreads();
  if (t < 128){
    float s0=0.f,s1=0.f,s2=0.f,s3=0.f;
    for (int d=0; d<128; d+=4){
      s0 = fmaf(u[d],   a2[(size_t) d   *128 + t], s0);
      s1 = fmaf(u[d+1], a2[(size_t)(d+1)*128 + t], s1);
      s2 = fmaf(u[d+2], a2[(size_t)(d+2)*128 + t], s2);
      s3 = fmaf(u[d+3], a2[(size_t)(d+3)*128 + t], s3);
    }
    float v = tanhf(s0+s1+s2+s3) * b2[t];
    #pragma unroll
    for (int k=32; k>=1; k>>=1) v += __shfl_xor(v, k);
    if ((t & 63) == 0) red[t>>6] = v;
  }
  __syncthreads();
  if (t == 0){
    float elast = red[0] + red[1];
    float mx=elast;
    for (int i=0;i<C_;i++) mx=fmaxf(mx,e2[i]);
    float ss=0.f;
    for (int i=0;i<C_;i++){ p2[i]=__expf(e2[i]-mx); ss+=p2[i]; }
    float pl = __expf(elast-mx); ss += pl;
    float inv=1.f/ss;
    for (int i=0;i<C_;i++) p2[i]*=inv;
    p2[C_] = pl*inv;
  }
  __syncthreads();
  if (t < 128){
    float s=0.f;
    for (int r=0;r<C_;r++) s = fmaf(p2[r], ctx[(size_t)r*128 + t], s);
    s = fmaf(p2[C_], u[t], s);
    ur[t] = s;
  }
  __syncthreads();
  int j = blockIdx.x*256 + t;
  if (j < NENT_){
    float s0=0.f,s1=0.f,s2=0.f,s3=0.f;
    for (int d=0; d<128; d+=4){
      s0 = fmaf(ur[d],   recW[(size_t) d   *NENT_ + j], s0);
      s1 = fmaf(ur[d+1], recW[(size_t)(d+1)*NENT_ + j], s1);
      s2 = fmaf(ur[d+2], recW[(size_t)(d+2)*NENT_ + j], s2);
      s3 = fmaf(ur[d+3], recW[(size_t)(d+3)*NENT_ + j], s3);
    }
    out[j] = s0+s1+s2+s3 + recb[j];
  }
}

// ---------------- launcher ----------------
extern "C" void kernel_launch(void* const* d_in, const int* in_sizes, int n_in,
                              void* d_out, int out_size, void* d_ws, size_t ws_size,
                              hipStream_t stream)
{
  auto f32 = [&](int i){ return (const float*)d_in[i]; };
  Ptr3i nodes = {{(const int*)d_in[24], (const int*)d_in[26], (const int*)d_in[28]}};
  Ptr3i edges = {{(const int*)d_in[25], (const int*)d_in[27], (const int*)d_in[29]}};

  // ---- workspace layout (~70 MB) ----
  char* base = (char*)d_ws;
  int*   cnt_all = (int*)base;
  int*   gcnt_e  = (int*)(base + 300064);
  int*   gcnt_n  = gcnt_e + NBKT*3;
  unsigned short* n_slot = (unsigned short*)(base + 300064 + 4096);
  float* m_mean  = (float*)((char*)n_slot + 7680000);
  unsigned short* m_buf = (unsigned short*)((char*)m_mean + 7680000);
  unsigned short* relbf = (unsigned short*)((char*)m_buf + 3840256);   // m_buf has +1 zero row (idx 15000)
  unsigned short* bfB   = (unsigned short*)((char*)relbf + 15360000);
  unsigned short* bfQ   = (unsigned short*)((char*)bfB + 65536);
  float* attentive = (float*)((char*)bfQ + 32768);
  float* user_repr = (float*)((char*)attentive + 25600);
  float* e1buf     = user_repr + 128;
  float* e2buf     = e1buf + 64;
  float* fpart = (float*)relbf;   // overlays relbf (dead after gemm_kv_mfma); 8*118*50*18*4 = 3.4 MB < 15.36 MB
  char* U = (char*)(e2buf + 64);
  unsigned* pe_part = (unsigned*)U;
  unsigned* pn_part = pe_part + (size_t)3*NBKT*BCAP;
  unsigned short* e_slot = (unsigned short*)(pn_part + (size_t)3*NBKT*BCAP);
  unsigned short* xb     = e_slot + (size_t)3*E_*CAPE_;   // 60001 rows (last = zero row)
  unsigned short* Kb  = (unsigned short*)U;
  unsigned short* Vtg = Kb + (size_t)H_*NK_*16;

  // ---- zero bin counters via graph memset node (frees prep/binA dependency) ----
  hipMemsetAsync(gcnt_e, 0, 4096, stream);

  // ---- merged prep + binA (independent; overlap in one launch) ----
  Ptr3f xs = {{f32(0), f32(1), f32(2)}};
  prep_binA<<<BINA_B + PB_TOT, 256, 0, stream>>>(xs, xb, f32(12), f32(14), bfB, m_buf,
                                   f32(3), f32(10), f32(11), bfQ, f32(20), f32(21), e2buf,
                                   nodes, edges, pe_part, pn_part, gcnt_e, gcnt_n);

  // ---- binB e-side ----
  binB_e<<<dim3(NBKT, 3), 256, 0, stream>>>(pe_part, gcnt_e, cnt_all, e_slot);

  // ---- binB n-side overlapped with group-per-edge gather ----
  egather_binbn<<<NBB + EG2, 256, 0, stream>>>(xb, cnt_all, e_slot, m_mean,
                                               pn_part, gcnt_n, cnt_all, n_slot);

  // ---- theta GEMM + node gather ----
  GemmB g;
  for (int mod=0; mod<3; mod++){
    g.A[mod] = m_mean + (size_t)mod*E_*D_;
    g.W[mod] = f32(4 + 2*mod);
    g.C[mod] = m_buf + (size_t)mod*E_*D_;
  }
  gemm_b<<<dim3((E_+63)/64, 3), 256, 0, stream>>>(g, E_);
  Ptr3f biases = {{f32(5), f32(7), f32(9)}};
  n_gather_g<<<dim3(N_/16, 3), 256, 0, stream>>>(m_buf, cnt_all, n_slot, biases, relbf);

  // ---- MHA ----
  gemm_kv_mfma<<<KVBLK, 256, 0, stream>>>(relbf, bfB, f32(13), f32(15), Kb, Vtg);
  flash3<<<dim3(NCH3, H_), 256, 0, stream>>>(Kb, Vtg, bfQ, fpart);
  merge_oproj_e1<<<C_, 512, 0, stream>>>(fpart, f32(16), f32(17), f32(18), f32(19),
                                         attentive, e1buf);

  // ---- fused tail + scores ----
  tail_scores<<<(NENT_+255)/256, 256, 0, stream>>>(attentive, f32(3), f32(20), f32(21),
                                                   e1buf, e2buf, f32(22), f32(23), (float*)d_out);
}

// Round 12
// 330.586 us; speedup vs baseline: 1.0786x; 1.0786x over previous
//
#include <hip/hip_runtime.h>
#include <hip/hip_bf16.h>

#define D_ 128
#define H_ 8
#define N_ 20000
#define NNZ_ 500000
#define E_ 5000
#define C_ 50
#define NENT_ 50000
#define NK_ (3*N_)
#define CAPE_ 192
#define CAPN_ 64
#define ENT_PB 4096
#define NBKT 157
#define BCAP 3648
#define ABLK 123
#define NCH3 118            // chunks per head, 512 keys each; 1 merged partial per chunk
#define KVBLK 235           // ceil(60000/256)
#define BINA_B (3*ABLK)     // 369 binA blocks, prefixed into prep_binA
#define NBB (3*NBKT)        // 471 binB n-side blocks, prefixed into egather kernel
#define EGB 944             // group-per-edge gather blocks (16 edges/block), 118 per XCD class

struct Ptr3f { const float* p[3]; };
struct Ptr3i { const int* p[3]; };
struct GemmB { const float* A[3]; const float* W[3]; unsigned short* C[3]; };

typedef short bf16x8 __attribute__((ext_vector_type(8)));
typedef float f32x4  __attribute__((ext_vector_type(4)));
typedef float f32x2  __attribute__((ext_vector_type(2)));

__device__ __forceinline__ unsigned short f2b(float f){
  unsigned u = __float_as_uint(f);
  u += 0x7FFFu + ((u>>16)&1u);
  return (unsigned short)(u>>16);
}
__device__ __forceinline__ unsigned pk2(float a, float b){
  return (unsigned)f2b(a) | ((unsigned)f2b(b) << 16);
}
__device__ __forceinline__ float blo(unsigned u){ return __uint_as_float(u<<16); }
__device__ __forceinline__ float bhi(unsigned u){ return __uint_as_float(u & 0xFFFF0000u); }

// group-gather batch: 8 member rows via group-uniform uint4 slot load; lane dl owns 16B of each row
#define GGATHER8(MB, SLOTP, J) { \
  uint4 sv = *(const uint4*)((SLOTP) + (J)); \
  int o0 = (int)(sv.x & 0xFFFFu) << 8, o1 = (int)(sv.x >> 16) << 8; \
  int o2 = (int)(sv.y & 0xFFFFu) << 8, o3 = (int)(sv.y >> 16) << 8; \
  int o4 = (int)(sv.z & 0xFFFFu) << 8, o5 = (int)(sv.z >> 16) << 8; \
  int o6 = (int)(sv.w & 0xFFFFu) << 8, o7 = (int)(sv.w >> 16) << 8; \
  uint4 u0 = *(const uint4*)((MB) + o0); \
  uint4 u1 = *(const uint4*)((MB) + o1); \
  uint4 u2 = *(const uint4*)((MB) + o2); \
  uint4 u3 = *(const uint4*)((MB) + o3); \
  uint4 u4 = *(const uint4*)((MB) + o4); \
  uint4 u5 = *(const uint4*)((MB) + o5); \
  uint4 u6 = *(const uint4*)((MB) + o6); \
  uint4 u7 = *(const uint4*)((MB) + o7); \
  a01 += (f32x2){blo(u0.x), bhi(u0.x)}; a23 += (f32x2){blo(u0.y), bhi(u0.y)}; \
  a45 += (f32x2){blo(u0.z), bhi(u0.z)}; a67 += (f32x2){blo(u0.w), bhi(u0.w)}; \
  a01 += (f32x2){blo(u1.x), bhi(u1.x)}; a23 += (f32x2){blo(u1.y), bhi(u1.y)}; \
  a45 += (f32x2){blo(u1.z), bhi(u1.z)}; a67 += (f32x2){blo(u1.w), bhi(u1.w)}; \
  a01 += (f32x2){blo(u2.x), bhi(u2.x)}; a23 += (f32x2){blo(u2.y), bhi(u2.y)}; \
  a45 += (f32x2){blo(u2.z), bhi(u2.z)}; a67 += (f32x2){blo(u2.w), bhi(u2.w)}; \
  a01 += (f32x2){blo(u3.x), bhi(u3.x)}; a23 += (f32x2){blo(u3.y), bhi(u3.y)}; \
  a45 += (f32x2){blo(u3.z), bhi(u3.z)}; a67 += (f32x2){blo(u3.w), bhi(u3.w)}; \
  a01 += (f32x2){blo(u4.x), bhi(u4.x)}; a23 += (f32x2){blo(u4.y), bhi(u4.y)}; \
  a45 += (f32x2){blo(u4.z), bhi(u4.z)}; a67 += (f32x2){blo(u4.w), bhi(u4.w)}; \
  a01 += (f32x2){blo(u5.x), bhi(u5.x)}; a23 += (f32x2){blo(u5.y), bhi(u5.y)}; \
  a45 += (f32x2){blo(u5.z), bhi(u5.z)}; a67 += (f32x2){blo(u5.w), bhi(u5.w)}; \
  a01 += (f32x2){blo(u6.x), bhi(u6.x)}; a23 += (f32x2){blo(u6.y), bhi(u6.y)}; \
  a45 += (f32x2){blo(u6.z), bhi(u6.z)}; a67 += (f32x2){blo(u6.w), bhi(u6.w)}; \
  a01 += (f32x2){blo(u7.x), bhi(u7.x)}; a23 += (f32x2){blo(u7.y), bhi(u7.y)}; \
  a45 += (f32x2){blo(u7.z), bhi(u7.z)}; a67 += (f32x2){blo(u7.w), bhi(u7.w)}; \
}

// ---------------- merged prep + binA (independent stages share one launch) ----------------
#define PB_PACK 7500
#define PB_Z    7628
#define PB_Q    7629
#define PB_CTX  7693
#define PB_TOT  7743
__global__ __launch_bounds__(256) void prep_binA(Ptr3f xs, unsigned short* __restrict__ xb,
    const float* __restrict__ Wk, const float* __restrict__ Wv, unsigned short* __restrict__ bfB,
    unsigned short* __restrict__ mzero,
    const float* __restrict__ ctx, const float* __restrict__ Wq, const float* __restrict__ bq,
    unsigned short* __restrict__ bfQ,
    const float* __restrict__ a2, const float* __restrict__ b2, float* __restrict__ e2,
    Ptr3i nodes, Ptr3i edges,
    unsigned* __restrict__ pe_part, unsigned* __restrict__ pn_part,
    int* __restrict__ gcnt_e, int* __restrict__ gcnt_n)
{
  const int t = threadIdx.x;
  if (blockIdx.x < BINA_B){
    // ================= binA =================
    __shared__ unsigned lbin[ENT_PB];
    __shared__ int cnt[256], off[256];
    __shared__ int gbase[NBKT];
    __shared__ int wsum[4];
    const int mod = blockIdx.x / ABLK;
    const int xblk = blockIdx.x - mod*ABLK;
    const int* nd = nodes.p[mod];
    const int* ed = edges.p[mod];
    const int base = xblk * ENT_PB;
    const int lane = t & 63, w = t >> 6;

    int myn[16], mye[16], pos[16];
    #pragma unroll
    for (int k=0;k<16;k++){
      int i = base + t + k*256;
      if (i < NNZ_){ myn[k]=nd[i]; mye[k]=ed[i]; }
      else { myn[k]=-1; mye[k]=-1; }
    }

    cnt[t] = 0;
    __syncthreads();
    #pragma unroll
    for (int k=0;k<16;k++)
      if (mye[k] >= 0) pos[k] = atomicAdd(&cnt[mye[k]>>5], 1);
    __syncthreads();
    {
      int v = cnt[t], s = v;
      #pragma unroll
      for (int d=1; d<64; d<<=1){ int u=__shfl_up(s,d); if (lane>=d) s+=u; }
      if (lane==63) wsum[w]=s;
      __syncthreads();
      int wb=0;
      for (int i=0;i<w;i++) wb+=wsum[i];
      off[t] = wb + s - v;
      __syncthreads();
    }
    #pragma unroll
    for (int k=0;k<16;k++)
      if (mye[k] >= 0)
        lbin[off[mye[k]>>5] + pos[k]] = ((unsigned)mye[k] << 15) | (unsigned)myn[k];
    if (t < NBKT && cnt[t] > 0) gbase[t] = atomicAdd(&gcnt_e[mod*NBKT + t], cnt[t]);
    __syncthreads();
    {
      int total = off[255];
      unsigned* dstreg = pe_part + (size_t)mod*NBKT*BCAP;
      for (int i=t; i<total; i+=256){
        unsigned pk = lbin[i];
        int b = pk >> 20;
        int gp = gbase[b] + (i - off[b]);
        if (gp < BCAP) dstreg[(size_t)b*BCAP + gp] = pk;
      }
    }
    __syncthreads();

    cnt[t] = 0;
    __syncthreads();
    #pragma unroll
    for (int k=0;k<16;k++)
      if (myn[k] >= 0) pos[k] = atomicAdd(&cnt[myn[k]>>7], 1);
    __syncthreads();
    {
      int v = cnt[t], s = v;
      #pragma unroll
      for (int d=1; d<64; d<<=1){ int u=__shfl_up(s,d); if (lane>=d) s+=u; }
      if (lane==63) wsum[w]=s;
      __syncthreads();
      int wb=0;
      for (int i=0;i<w;i++) wb+=wsum[i];
      off[t] = wb + s - v;
      __syncthreads();
    }
    #pragma unroll
    for (int k=0;k<16;k++)
      if (myn[k] >= 0)
        lbin[off[myn[k]>>7] + pos[k]] = ((unsigned)myn[k] << 13) | (unsigned)mye[k];
    if (t < NBKT && cnt[t] > 0) gbase[t] = atomicAdd(&gcnt_n[mod*NBKT + t], cnt[t]);
    __syncthreads();
    {
      int total = off[255];
      unsigned* dstreg = pn_part + (size_t)mod*NBKT*BCAP;
      for (int i=t; i<total; i+=256){
        unsigned pk = lbin[i];
        int b = pk >> 20;
        int gp = gbase[b] + (i - off[b]);
        if (gp < BCAP) dstreg[(size_t)b*BCAP + gp] = pk;
      }
    }
    return;
  }

  // ================= prep =================
  int bid = blockIdx.x - BINA_B;
  if (bid < PB_PACK){
    int mod = bid / 2500, blk = bid - mod*2500;
    int i4 = blk*256 + t;
    float4 v = *(const float4*)(xs.p[mod] + (size_t)i4*4);
    ushort4 o; o.x=f2b(v.x); o.y=f2b(v.y); o.z=f2b(v.z); o.w=f2b(v.w);
    *(ushort4*)(xb + (size_t)mod*N_*D_ + (size_t)i4*4) = o;
  } else if (bid < PB_Z){
    int idx = (bid - PB_PACK)*256 + t;     // 32768
    int j  = idx & 7;
    int L  = (idx >> 3) & 63;
    int kb = (idx >> 9) & 3;
    int tt = idx >> 11;
    int k = kb*32 + (L>>4)*8 + j;
    int x = L & 15;
    float v = (tt < 8) ? Wk[(size_t)k*128 + tt*16 + x] : Wv[(size_t)k*128 + (tt-8)*16 + x];
    bfB[idx] = f2b(v);
  } else if (bid == PB_Z){
    if (t < 64)       ((unsigned*)(xb    + (size_t)60000*128))[t]    = 0u;   // zero gather row (e-side)
    else if (t < 128) ((unsigned*)(mzero + (size_t)15000*128))[t-64] = 0u;   // zero gather row (n-side)
  } else if (bid < PB_CTX){
    int idx = (bid - PB_Q)*256 + t;        // 16384
    int j  = idx & 7;
    int L  = (idx >> 3) & 63;
    int qt = (idx >> 9) & 3;
    int h  = idx >> 11;
    int k  = ((L>>4)&3)*8 + j;
    int q  = qt*16 + (L & 15);
    float val = 0.f;
    if (k < 16 && q < C_){
      const float* cr = ctx + (size_t)q*128;
      const float* wc = Wq + h*16 + k;
      float s0=0.f,s1=0.f,s2=0.f,s3=0.f;
      for (int d=0; d<128; d+=4){
        s0 = fmaf(cr[d],   wc[(size_t) d   *128], s0);
        s1 = fmaf(cr[d+1], wc[(size_t)(d+1)*128], s1);
        s2 = fmaf(cr[d+2], wc[(size_t)(d+2)*128], s2);
        s3 = fmaf(cr[d+3], wc[(size_t)(d+3)*128], s3);
      }
      val = 0.25f * (s0+s1+s2+s3 + bq[h*16+k]);
    }
    bfQ[idx] = f2b(val);
  } else {
    __shared__ float row[128];
    __shared__ float ps[128][2];
    __shared__ float red[2];
    int q = bid - PB_CTX;
    if (t < 128) row[t] = ctx[(size_t)q*128 + t];
    __syncthreads();
    int c = t & 127, half = t >> 7;
    float s = 0.f;
    int d0 = half*64;
    for (int d=d0; d<d0+64; d+=4){
      s = fmaf(row[d],   a2[(size_t) d   *128 + c], s);
      s = fmaf(row[d+1], a2[(size_t)(d+1)*128 + c], s);
      s = fmaf(row[d+2], a2[(size_t)(d+2)*128 + c], s);
      s = fmaf(row[d+3], a2[(size_t)(d+3)*128 + c], s);
    }
    ps[c][half] = s;
    __syncthreads();
    if (t < 128){
      float v = tanhf(ps[t][0] + ps[t][1]) * b2[t];
      #pragma unroll
      for (int k=32; k>=1; k>>=1) v += __shfl_xor(v, k);
      if ((t & 63) == 0) red[t>>6] = v;
    }
    __syncthreads();
    if (t == 0) e2[q] = red[0] + red[1];
  }
}

// ---------------- binB e-side only (dummy-padded slot rows) ----------------
__global__ __launch_bounds__(256) void binB_e(const unsigned* __restrict__ pe_part,
    const int* __restrict__ gcnt_e, int* __restrict__ cnt_all,
    unsigned short* __restrict__ e_slot)
{
  __shared__ unsigned short ls[32*CAPE_];
  __shared__ int lc[32];
  const int mod = blockIdx.y, b = blockIdx.x, t = threadIdx.x;
  {
    unsigned short dmy = (unsigned short)(60000 - mod*20000);
    unsigned dd = (unsigned)dmy * 0x10001u;
    unsigned* lsu32 = (unsigned*)ls;
    for (int i=t; i<32*CAPE_/2; i+=256) lsu32[i] = dd;
  }
  if (t < 32) lc[t] = 0;
  __syncthreads();
  int cnt = gcnt_e[mod*NBKT + b];
  if (cnt > BCAP) cnt = BCAP;
  const unsigned* src = pe_part + ((size_t)mod*NBKT + b)*BCAP;
  for (int i=t; i<cnt; i+=256){
    unsigned pk = src[i];
    int el = (pk >> 15) - b*32;
    int n  = pk & 0x7FFF;
    int p = atomicAdd(&lc[el], 1);
    if (p < CAPE_) ls[el*CAPE_ + p] = (unsigned short)n;
  }
  __syncthreads();
  int rows = E_ - b*32; if (rows > 32) rows = 32;
  if (t < rows) cnt_all[mod*(E_+N_) + b*32 + t] = lc[t];
  const unsigned* lsu = (const unsigned*)ls;
  unsigned* dst = (unsigned*)(e_slot + ((size_t)mod*E_ + b*32)*CAPE_);
  int tot = rows*CAPE_/2;
  for (int i=t; i<tot; i+=256) dst[i] = lsu[i];
}

// ---------------- merged binB n-side + XCD-pinned group-per-edge gather ----------------
// blocks [0, NBB): binB n-side; blocks [NBB, NBB+EGB): e_gather, 16 edges/block,
// 16-lane group per edge (zero cross-lane ops), XCD class (blockIdx&7) pinned to one mod:
// {0,1,2}->mod0, {3,4,5}->mod1, {6,7}->mod2 (+77 helper blocks from mod0/1 classes).
__global__ __launch_bounds__(256) void egather_binbn(const unsigned short* __restrict__ xb,
    const int* __restrict__ cnt_all, const unsigned short* __restrict__ e_slot,
    float* __restrict__ m_mean,
    const unsigned* __restrict__ pn_part, const int* __restrict__ gcnt_n,
    int* __restrict__ cnt_all_w, unsigned short* __restrict__ n_slot)
{
  __shared__ unsigned short ls[128*CAPN_];
  __shared__ int lc[128];
  const int t = threadIdx.x;
  if (blockIdx.x < NBB){
    // ================= binB n-side =================
    const int mod = blockIdx.x / NBKT, b = blockIdx.x - mod*NBKT;
    {
      unsigned short dmy = (unsigned short)(15000 - mod*5000);
      unsigned dd = (unsigned)dmy * 0x10001u;
      unsigned* lsu32 = (unsigned*)ls;
      for (int i=t; i<128*CAPN_/2; i+=256) lsu32[i] = dd;
    }
    if (t < 128) lc[t] = 0;
    __syncthreads();
    int cnt = gcnt_n[mod*NBKT + b];
    if (cnt > BCAP) cnt = BCAP;
    const unsigned* src = pn_part + ((size_t)mod*NBKT + b)*BCAP;
    for (int i=t; i<cnt; i+=256){
      unsigned pk = src[i];
      int nl = (pk >> 13) - b*128;
      int e  = pk & 0x1FFF;
      int p = atomicAdd(&lc[nl], 1);
      if (p < CAPN_) ls[nl*CAPN_ + p] = (unsigned short)e;
    }
    __syncthreads();
    int rows = N_ - b*128; if (rows > 128) rows = 128;
    if (t < rows) cnt_all_w[mod*(E_+N_) + E_ + b*128 + t] = lc[t];
    const unsigned* lsu = (const unsigned*)ls;
    unsigned* dst = (unsigned*)(n_slot + ((size_t)mod*N_ + b*128)*CAPN_);
    int tot = rows*CAPN_/2;
    for (int i=t; i<tot; i+=256) dst[i] = lsu[i];
    return;
  }

  // ================= XCD-pinned group-per-edge e_gather =================
  const int bb = blockIdx.x - NBB;
  const int x = blockIdx.x & 7;               // physical XCD class (heuristic)
  const int j = bb >> 3;                      // index within class, [0,118)
  int mod, r;
  if (x < 6){
    mod = x / 3;
    int li = x - mod*3;
    int c = 105 - (li > 0);                   // own-mod blocks: 105/104/104 -> 313
    if (j < c){
      r = j*3 + li;                           // covers [0,313)
    } else {
      int hb = (li == 0) ? 0 : ((li == 1) ? 13 : 27);
      int hg = mod*41 + hb + (j - c);         // helper index [0,82)
      if (hg >= 77) return;
      mod = 2; r = 236 + hg;                  // mod2 tail [236,313)
    }
  } else {
    mod = 2; r = j*2 + (x - 6);               // covers [0,236)
  }
  const int w = t >> 6, lane = t & 63;
  const int g = lane >> 4, dl = lane & 15;
  int e = r*16 + w*4 + g;
  if (e >= E_) return;
  const char* mb = (const char*)(xb + (size_t)mod*N_*D_) + dl*16;
  int cnt = cnt_all[mod*(E_+N_) + e];
  int c2 = (cnt < CAPE_) ? cnt : CAPE_;
  int m8 = (c2 + 7) & ~7;                    // <= 192; tail dummy rows add 0
  const unsigned short* slot = e_slot + ((size_t)mod*E_ + e)*CAPE_;
  f32x2 a01={0.f,0.f}, a23={0.f,0.f}, a45={0.f,0.f}, a67={0.f,0.f};

  for (int jj=0; jj<m8; jj+=8) GGATHER8(mb, slot, jj)

  float inv = 1.f / fmaxf((float)cnt, 1.f);
  float* dst = m_mean + ((size_t)mod*E_ + e)*128 + dl*8;
  float4 o1; o1.x=a01.x*inv; o1.y=a01.y*inv; o1.z=a23.x*inv; o1.w=a23.y*inv;
  float4 o2; o2.x=a45.x*inv; o2.y=a45.y*inv; o2.z=a67.x*inv; o2.w=a67.y*inv;
  *(float4*)dst = o1;
  *(float4*)(dst + 4) = o2;
}

// ---------------- batched theta GEMM ----------------
__global__ __launch_bounds__(256) void gemm_b(GemmB g, int M)
{
  const float* A = g.A[blockIdx.y];
  const float* W = g.W[blockIdx.y];
  unsigned short* Cout = g.C[blockIdx.y];
  __shared__ float As[64][33];
  __shared__ float Ws[32][128];
  const int t  = threadIdx.x;
  const int br = blockIdx.x * 64;
  const int r0 = (t >> 5) * 8;
  const int c0 = (t & 31) * 4;
  const int lr = t >> 2;
  const int lk = (t & 3) * 8;
  const int wk = t >> 5;

  float acc[8][4];
  #pragma unroll
  for (int i=0;i<8;i++){ acc[i][0]=0.f; acc[i][1]=0.f; acc[i][2]=0.f; acc[i][3]=0.f; }

  for (int kb=0; kb<128; kb+=32){
    float av[8];
    const int grow = br + lr;
    if (grow < M){
      const float* p = A + (size_t)grow*128 + kb + lk;
      float4 a = ((const float4*)p)[0], b = ((const float4*)p)[1];
      av[0]=a.x;av[1]=a.y;av[2]=a.z;av[3]=a.w;av[4]=b.x;av[5]=b.y;av[6]=b.z;av[7]=b.w;
    } else {
      #pragma unroll
      for (int j=0;j<8;j++) av[j]=0.f;
    }
    float4 wv4[4];
    #pragma unroll
    for (int kk=0;kk<4;kk++) wv4[kk] = *(const float4*)&W[(size_t)(kb + wk + kk*8)*128 + c0];

    __syncthreads();
    #pragma unroll
    for (int j=0;j<8;j++) As[lr][lk+j] = av[j];
    #pragma unroll
    for (int kk=0;kk<4;kk++) *(float4*)&Ws[wk + kk*8][c0] = wv4[kk];
    __syncthreads();

    #pragma unroll
    for (int k=0;k<32;k++){
      float4 wv = *(const float4*)&Ws[k][c0];
      #pragma unroll
      for (int i=0;i<8;i++){
        float a = As[r0+i][k];
        acc[i][0] = fmaf(a, wv.x, acc[i][0]);
        acc[i][1] = fmaf(a, wv.y, acc[i][1]);
        acc[i][2] = fmaf(a, wv.z, acc[i][2]);
        acc[i][3] = fmaf(a, wv.w, acc[i][3]);
      }
    }
  }

  #pragma unroll
  for (int i=0;i<8;i++){
    int gr = br + r0 + i;
    if (gr < M){
      ushort4 o;
      o.x=f2b(acc[i][0]); o.y=f2b(acc[i][1]); o.z=f2b(acc[i][2]); o.w=f2b(acc[i][3]);
      *(ushort4*)(Cout + (size_t)gr*128 + c0) = o;
    }
  }
}

// ---------------- group-per-node gather-mean + bias -> bf16 related ----------------
__global__ __launch_bounds__(256) void n_gather_g(const unsigned short* __restrict__ m_buf,
    const int* __restrict__ cnt_all, const unsigned short* __restrict__ n_slot,
    Ptr3f biases, unsigned short* __restrict__ relbf)
{
  const int mod = blockIdx.y;
  const int t = threadIdx.x, w = t >> 6, lane = t & 63;
  const int g = lane >> 4, dl = lane & 15;
  const int n = blockIdx.x*16 + w*4 + g;
  const char* mb = (const char*)(m_buf + (size_t)mod*E_*D_) + dl*16;
  int cnt = cnt_all[mod*(E_+N_) + E_ + n];
  int c2 = (cnt < CAPN_) ? cnt : CAPN_;
  int m8 = (c2 + 7) & ~7;                    // <= 64; tail dummy rows add 0
  const unsigned short* slot = n_slot + ((size_t)mod*N_ + n)*CAPN_;
  f32x2 a01={0.f,0.f}, a23={0.f,0.f}, a45={0.f,0.f}, a67={0.f,0.f};

  for (int j=0; j<m8; j+=8) GGATHER8(mb, slot, j)

  float inv = 1.f / fmaxf((float)cnt, 1.f);
  const float* bs = biases.p[mod] + dl*8;
  uint4 o;
  o.x = pk2(a01.x*inv + bs[0], a01.y*inv + bs[1]);
  o.y = pk2(a23.x*inv + bs[2], a23.y*inv + bs[3]);
  o.z = pk2(a45.x*inv + bs[4], a45.y*inv + bs[5]);
  o.w = pk2(a67.x*inv + bs[6], a67.y*inv + bs[7]);
  *(uint4*)(relbf + ((size_t)mod*N_ + n)*128 + dl*8) = o;
}

// ---------------- MFMA KV GEMM v2: B from L2, V staged in LDS for coalesced writes ----------------
__global__ __launch_bounds__(256) void gemm_kv_mfma(const unsigned short* __restrict__ relbf,
    const unsigned short* __restrict__ bfB, const float* __restrict__ bk,
    const float* __restrict__ bv, unsigned short* __restrict__ Kb,
    unsigned short* __restrict__ Vtg)
{
  __shared__ unsigned short Vs[128][72];   // 18.4 KB, 144B rows (16B-aligned)
  const int t = threadIdx.x, w = t >> 6, L = t & 63;
  const int m = L & 15, quad = L >> 4, x = m;
  const int rowbase = blockIdx.x*256;

  for (int g = 0; g < 4; g++){
    const int j0 = rowbase + g*64 + w*16;

    bf16x8 a[4];
    {
      int row = j0 + m;
      int rowc = (row < NK_) ? row : (NK_-1);
      #pragma unroll
      for (int kb=0; kb<4; kb++)
        a[kb] = *(const bf16x8*)(relbf + (size_t)rowc*128 + kb*32 + quad*8);
    }

    f32x4 acc[16];
    #pragma unroll
    for (int tt=0; tt<16; tt++) acc[tt] = (f32x4){0.f,0.f,0.f,0.f};

    #pragma unroll
    for (int kb=0; kb<4; kb++){
      #pragma unroll
      for (int tt=0; tt<16; tt++){
        bf16x8 b = *(const bf16x8*)(bfB + (((tt*4 + kb)*64 + L) << 3));
        acc[tt] = __builtin_amdgcn_mfma_f32_16x16x32_bf16(a[kb], b, acc[tt], 0, 0, 0);
      }
    }

    // ---- K: direct stores (already 32B-contiguous across x lanes) ----
    #pragma unroll
    for (int tt=0; tt<8; tt++){
      float bias = bk[tt*16 + x];
      unsigned p0, p1;
      asm("v_cvt_pk_bf16_f32 %0, %1, %2" : "=v"(p0) : "v"(acc[tt][0]+bias), "v"(acc[tt][1]+bias));
      asm("v_cvt_pk_bf16_f32 %0, %1, %2" : "=v"(p1) : "v"(acc[tt][2]+bias), "v"(acc[tt][3]+bias));
      int jrb = j0 + quad*4;
      if (jrb + 3 < NK_){
        Kb[(((size_t)tt*NK_ + jrb    ) << 4) + x] = (unsigned short)p0;
        Kb[(((size_t)tt*NK_ + jrb + 1) << 4) + x] = (unsigned short)(p0 >> 16);
        Kb[(((size_t)tt*NK_ + jrb + 2) << 4) + x] = (unsigned short)p1;
        Kb[(((size_t)tt*NK_ + jrb + 3) << 4) + x] = (unsigned short)(p1 >> 16);
      } else {
        if (jrb     < NK_) Kb[(((size_t)tt*NK_ + jrb    ) << 4) + x] = (unsigned short)p0;
        if (jrb + 1 < NK_) Kb[(((size_t)tt*NK_ + jrb + 1) << 4) + x] = (unsigned short)(p0 >> 16);
        if (jrb + 2 < NK_) Kb[(((size_t)tt*NK_ + jrb + 2) << 4) + x] = (unsigned short)p1;
        if (jrb + 3 < NK_) Kb[(((size_t)tt*NK_ + jrb + 3) << 4) + x] = (unsigned short)(p1 >> 16);
      }
    }

    // ---- V: stage to LDS (col-contiguous matches register layout) ----
    #pragma unroll
    for (int tt=8; tt<16; tt++){
      int h = tt - 8;
      float bias = bv[h*16 + x];
      unsigned p0, p1;
      asm("v_cvt_pk_bf16_f32 %0, %1, %2" : "=v"(p0) : "v"(acc[tt][0]+bias), "v"(acc[tt][1]+bias));
      asm("v_cvt_pk_bf16_f32 %0, %1, %2" : "=v"(p1) : "v"(acc[tt][2]+bias), "v"(acc[tt][3]+bias));
      int col = w*16 + quad*4;
      *(unsigned*)&Vs[h*16 + x][col]     = p0;
      *(unsigned*)&Vs[h*16 + x][col + 2] = p1;
    }
    __syncthreads();

    // ---- V flush: 128 rows x 64 cols, 64B contiguous per thread ----
    {
      int row = t >> 1, half = t & 1;
      int c0 = half*32;
      int jr0 = rowbase + g*64 + c0;
      const unsigned short* src = &Vs[row][c0];
      unsigned short* dstp = Vtg + (size_t)row*NK_ + jr0;
      if (jr0 + 31 < NK_){
        ((uint4*)dstp)[0] = ((const uint4*)src)[0];
        ((uint4*)dstp)[1] = ((const uint4*)src)[1];
        ((uint4*)dstp)[2] = ((const uint4*)src)[2];
        ((uint4*)dstp)[3] = ((const uint4*)src)[3];
      } else {
        for (int c=0; c<32; c++) if (jr0 + c < NK_) dstp[c] = src[c];
      }
    }
    __syncthreads();
  }
}

// ---------------- MFMA flash with in-block 4-wave merge (512-key chunks for occupancy) ----------------
__global__ __launch_bounds__(256) void flash3(const unsigned short* __restrict__ Kb,
    const unsigned short* __restrict__ Vtg, const unsigned short* __restrict__ bfQ,
    float* __restrict__ part)
{
  __shared__ unsigned short P_lds[4][64][40];
  __shared__ float mbuf[4][64][18];
  const int c = blockIdx.x, h = blockIdx.y;
  const int t = threadIdx.x, w = t >> 6, L = t & 63;
  const int n = L & 15, quad = L >> 4;

  bf16x8 qb[4];
  #pragma unroll
  for (int qt=0; qt<4; qt++)
    qb[qt] = *(const bf16x8*)(bfQ + (((h*4 + qt)*64 + L) << 3));

  float Mc[4], Lc[4];
  f32x4 accq[4];
  #pragma unroll
  for (int qt=0; qt<4; qt++){ Mc[qt] = -INFINITY; Lc[qt] = 0.f; accq[qt] = (f32x4){0.f,0.f,0.f,0.f}; }

  const int base = c*512 + w*128;
  unsigned* Pw = (unsigned*)&P_lds[w][0][0];

  for (int tile=0; tile<4; tile++){
    const int j0 = base + tile*32;
    const bool dead = (j0 >= NK_);

    bf16x8 a0 = (bf16x8){0,0,0,0,0,0,0,0};
    bf16x8 a1 = a0;
    if (quad < 2){
      int k0 = j0 + n;      if (k0 > NK_-1) k0 = NK_-1;
      int k1 = j0 + 16 + n; if (k1 > NK_-1) k1 = NK_-1;
      a0 = *(const bf16x8*)(Kb + (((size_t)h*NK_ + k0) << 4) + quad*8);
      a1 = *(const bf16x8*)(Kb + (((size_t)h*NK_ + k1) << 4) + quad*8);
    }
    f32x4 s0[4], s1[4];
    #pragma unroll
    for (int qt=0; qt<4; qt++){
      s0[qt] = __builtin_amdgcn_mfma_f32_16x16x32_bf16(a0, qb[qt], (f32x4){0.f,0.f,0.f,0.f}, 0,0,0);
      s1[qt] = __builtin_amdgcn_mfma_f32_16x16x32_bf16(a1, qb[qt], (f32x4){0.f,0.f,0.f,0.f}, 0,0,0);
    }

    #pragma unroll
    for (int qt=0; qt<4; qt++){
      float mt = s0[qt][0];
      mt = fmaxf(mt, s0[qt][1]); mt = fmaxf(mt, s0[qt][2]); mt = fmaxf(mt, s0[qt][3]);
      mt = fmaxf(mt, s1[qt][0]); mt = fmaxf(mt, s1[qt][1]);
      mt = fmaxf(mt, s1[qt][2]); mt = fmaxf(mt, s1[qt][3]);
      mt = fmaxf(mt, __shfl_xor(mt, 16));
      mt = fmaxf(mt, __shfl_xor(mt, 32));
      float Mn = fmaxf(Mc[qt], mt);
      float corr = __expf(Mc[qt] - Mn);
      Mc[qt] = Mn;
      float p0[4], p1[4];
      #pragma unroll
      for (int r=0;r<4;r++){
        p0[r] = __expf(s0[qt][r] - Mn);
        p1[r] = __expf(s1[qt][r] - Mn);
      }
      if (dead){
        #pragma unroll
        for (int r=0;r<4;r++){ p0[r]=0.f; p1[r]=0.f; }
      }
      float lt = p0[0]+p0[1]+p0[2]+p0[3]+p1[0]+p1[1]+p1[2]+p1[3];
      lt += __shfl_xor(lt, 16);
      lt += __shfl_xor(lt, 32);
      Lc[qt] = Lc[qt]*corr + lt;
      int rb = (qt*16 + n)*20;
      Pw[rb + quad*2]     = pk2(p0[0], p0[1]);
      Pw[rb + quad*2 + 1] = pk2(p0[2], p0[3]);
      Pw[rb + 8 + quad*2]     = pk2(p1[0], p1[1]);
      Pw[rb + 8 + quad*2 + 1] = pk2(p1[2], p1[3]);
      #pragma unroll
      for (int r=0;r<4;r++){
        float cr = __shfl(corr, quad*4 + r);
        accq[qt][r] *= cr;
      }
    }
    __syncthreads();

    bf16x8 bv_;
    {
      int va = j0 + quad*8; if (va > NK_-8) va = NK_-8;
      bv_ = *(const bf16x8*)(Vtg + ((size_t)(h*16 + n))*NK_ + va);
    }
    #pragma unroll
    for (int qt=0; qt<4; qt++){
      bf16x8 pa = *(const bf16x8*)&P_lds[w][qt*16 + n][quad*8];
      accq[qt] = __builtin_amdgcn_mfma_f32_16x16x32_bf16(pa, bv_, accq[qt], 0,0,0);
    }
    __syncthreads();
  }

  #pragma unroll
  for (int qt=0; qt<4; qt++){
    #pragma unroll
    for (int r=0; r<4; r++)
      mbuf[w][qt*16 + quad*4 + r][2 + n] = accq[qt][r];
    if (quad == 0){
      mbuf[w][qt*16 + n][0] = Mc[qt];
      mbuf[w][qt*16 + n][1] = Lc[qt];
    }
  }
  __syncthreads();
  if (t < C_){
    float M = mbuf[0][t][0], Lm = mbuf[0][t][1];
    float A[16];
    #pragma unroll
    for (int i=0;i<16;i++) A[i] = mbuf[0][t][2+i];
    #pragma unroll
    for (int ww=1; ww<4; ww++){
      float pm = mbuf[ww][t][0], pl = mbuf[ww][t][1];
      if (pl > 0.f){
        float mn = fmaxf(M, pm);
        float c1 = __expf(M - mn), c2 = __expf(pm - mn);
        Lm = Lm*c1 + pl*c2;
        #pragma unroll
        for (int i=0;i<16;i++) A[i] = A[i]*c1 + mbuf[ww][t][2+i]*c2;
        M = mn;
      }
    }
    float* pp = part + ((size_t)(h*NCH3 + c)*C_ + t)*18;
    pp[0] = M; pp[1] = Lm;
    #pragma unroll
    for (int i=0;i<16;i++) pp[2+i] = A[i];
  }
}

// ---------------- wave-parallel flash-merge + O-projection + e1 row ----------------
__global__ __launch_bounds__(512) void merge_oproj_e1(const float* __restrict__ part,
    const float* __restrict__ Wo, const float* __restrict__ bo,
    const float* __restrict__ a1, const float* __restrict__ b1,
    float* __restrict__ attentive, float* __restrict__ e1)
{
  __shared__ float row[128];
  __shared__ float ps[128][4];
  __shared__ float orow[128];
  __shared__ float red[2];
  const int q = blockIdx.x, t = threadIdx.x;
  const int h = t >> 6, lane = t & 63;

  // ---- stage A: wave h merges NCH3 chunk partials for (h, q) ----
  {
    float M = -1e30f, L = 0.f;
    float A[16];
    #pragma unroll
    for (int i=0;i<16;i++) A[i] = 0.f;

    #pragma unroll
    for (int cc=0; cc<2; cc++){
      int c = lane + cc*64;
      if (c < NCH3){
        const float* p = part + ((size_t)(h*NCH3 + c)*C_ + q)*18;
        float pm = p[0], pl = p[1];
        if (pl > 0.f){
          float Mn = fmaxf(M, pm);
          float w1 = __expf(M - Mn), w2 = __expf(pm - Mn);
          L = L*w1 + pl*w2;
          #pragma unroll
          for (int i=0;i<16;i++) A[i] = fmaf(A[i], w1, p[2+i]*w2);
          M = Mn;
        }
      }
    }
    // 6-round butterfly merge across the wave
    #pragma unroll
    for (int d=32; d>=1; d>>=1){
      float pm = __shfl_xor(M, d);
      float pl = __shfl_xor(L, d);
      float Ao[16];
      #pragma unroll
      for (int i=0;i<16;i++) Ao[i] = __shfl_xor(A[i], d);
      float Mn = fmaxf(M, pm);
      float w1 = __expf(M - Mn), w2 = __expf(pm - Mn);
      L = L*w1 + pl*w2;
      #pragma unroll
      for (int i=0;i<16;i++) A[i] = fmaf(A[i], w1, Ao[i]*w2);
      M = Mn;
    }
    if (lane == 0){
      float invL = 1.f / L;
      #pragma unroll
      for (int i=0;i<16;i++) row[h*16 + i] = A[i]*invL;
    }
  }
  __syncthreads();

  // ---- stage B: O-projection (4-way d-split over 512 threads) ----
  const int c = t & 127, seg = t >> 7;
  {
    float s = 0.f;
    int d0 = seg*32;
    for (int d=d0; d<d0+32; d+=4){
      s = fmaf(row[d],   Wo[(size_t) d   *128 + c], s);
      s = fmaf(row[d+1], Wo[(size_t)(d+1)*128 + c], s);
      s = fmaf(row[d+2], Wo[(size_t)(d+2)*128 + c], s);
      s = fmaf(row[d+3], Wo[(size_t)(d+3)*128 + c], s);
    }
    ps[c][seg] = s;
  }
  __syncthreads();
  if (t < 128){
    float o = ps[t][0]+ps[t][1]+ps[t][2]+ps[t][3] + bo[t];
    attentive[(size_t)q*128 + t] = o;
    orow[t] = o;
  }
  __syncthreads();
  // ---- e1 row: tanh(orow @ a1) @ b1 ----
  {
    float s = 0.f;
    int d0 = seg*32;
    for (int d=d0; d<d0+32; d+=4){
      s = fmaf(orow[d],   a1[(size_t) d   *128 + c], s);
      s = fmaf(orow[d+1], a1[(size_t)(d+1)*128 + c], s);
      s = fmaf(orow[d+2], a1[(size_t)(d+2)*128 + c], s);
      s = fmaf(orow[d+3], a1[(size_t)(d+3)*128 + c], s);
    }
    ps[c][seg] = s;
  }
  __syncthreads();
  if (t < 128){
    float v = tanhf(ps[t][0]+ps[t][1]+ps[t][2]+ps[t][3]) * b1[t];
    #pragma unroll
    for (int k=32; k>=1; k>>=1) v += __shfl_xor(v, k);
    if ((t & 63) == 0) red[t>>6] = v;
  }
  __syncthreads();
  if (t == 0) e1[q] = red[0] + red[1];
}

// ---------------- fused tail + scores ----------------
__global__ __launch_bounds__(256) void tail_scores(const float* __restrict__ attentive,
    const float* __restrict__ ctx, const float* __restrict__ a2, const float* __restrict__ b2,
    const float* __restrict__ e1, const float* __restrict__ e2,
    const float* __restrict__ recW, const float* __restrict__ recb, float* __restrict__ out)
{
  __shared__ float p[64];
  __shared__ float u[128];
  __shared__ float red[2];
  __shared__ float p2[64];
  __shared__ float ur[128];
  const int t = threadIdx.x;

  if (t == 0){
    float mx=-INFINITY;
    for (int i=0;i<C_;i++) mx=fmaxf(mx,e1[i]);
    float ss=0.f;
    for (int i=0;i<C_;i++){ p[i]=__expf(e1[i]-mx); ss+=p[i]; }
    float inv=1.f/ss;
    for (int i=0;i<C_;i++) p[i]*=inv;
  }
  __syncthreads();
  if (t < 128){
    float s=0.f;
    for (int r=0;r<C_;r++) s = fmaf(p[r], attentive[(size_t)r*128 + t], s);
    u[t] = s;
  }
  __syncthreads();
  if (t < 128){
    float s0=0.f,s1=0.f,s2=0.f,s3=0.f;
    for (int d=0; d<128; d+=4){
      s0 = fmaf(u[d],   a2[(size_t) d   *128 + t], s0);
      s1 = fmaf(u[d+1], a2[(size_t)(d+1)*128 + t], s1);
      s2 = fmaf(u[d+2], a2[(size_t)(d+2)*128 + t], s2);
      s3 = fmaf(u[d+3], a2[(size_t)(d+3)*128 + t], s3);
    }
    float v = tanhf(s0+s1+s2+s3) * b2[t];
    #pragma unroll
    for (int k=32; k>=1; k>>=1) v += __shfl_xor(v, k);
    if ((t & 63) == 0) red[t>>6] = v;
  }
  __syncthreads();
  if (t == 0){
    float elast = red[0] + red[1];
    float mx=elast;
    for (int i=0;i<C_;i++) mx=fmaxf(mx,e2[i]);
    float ss=0.f;
    for (int i=0;i<C_;i++){ p2[i]=__expf(e2[i]-mx); ss+=p2[i]; }
    float pl = __expf(elast-mx); ss += pl;
    float inv=1.f/ss;
    for (int i=0;i<C_;i++) p2[i]*=inv;
    p2[C_] = pl*inv;
  }
  __syncthreads();
  if (t < 128){
    float s=0.f;
    for (int r=0;r<C_;r++) s = fmaf(p2[r], ctx[(size_t)r*128 + t], s);
    s = fmaf(p2[C_], u[t], s);
    ur[t] = s;
  }
  __syncthreads();
  int j = blockIdx.x*256 + t;
  if (j < NENT_){
    float s0=0.f,s1=0.f,s2=0.f,s3=0.f;
    for (int d=0; d<128; d+=4){
      s0 = fmaf(ur[d],   recW[(size_t) d   *NENT_ + j], s0);
      s1 = fmaf(ur[d+1], recW[(size_t)(d+1)*NENT_ + j], s1);
      s2 = fmaf(ur[d+2], recW[(size_t)(d+2)*NENT_ + j], s2);
      s3 = fmaf(ur[d+3], recW[(size_t)(d+3)*NENT_ + j], s3);
    }
    out[j] = s0+s1+s2+s3 + recb[j];
  }
}

// ---------------- launcher ----------------
extern "C" void kernel_launch(void* const* d_in, const int* in_sizes, int n_in,
                              void* d_out, int out_size, void* d_ws, size_t ws_size,
                              hipStream_t stream)
{
  auto f32 = [&](int i){ return (const float*)d_in[i]; };
  Ptr3i nodes = {{(const int*)d_in[24], (const int*)d_in[26], (const int*)d_in[28]}};
  Ptr3i edges = {{(const int*)d_in[25], (const int*)d_in[27], (const int*)d_in[29]}};

  // ---- workspace layout (~70 MB) ----
  char* base = (char*)d_ws;
  int*   cnt_all = (int*)base;
  int*   gcnt_e  = (int*)(base + 300064);
  int*   gcnt_n  = gcnt_e + NBKT*3;
  unsigned short* n_slot = (unsigned short*)(base + 300064 + 4096);
  float* m_mean  = (float*)((char*)n_slot + 7680000);
  unsigned short* m_buf = (unsigned short*)((char*)m_mean + 7680000);
  unsigned short* relbf = (unsigned short*)((char*)m_buf + 3840256);   // m_buf has +1 zero row (idx 15000)
  unsigned short* bfB   = (unsigned short*)((char*)relbf + 15360000);
  unsigned short* bfQ   = (unsigned short*)((char*)bfB + 65536);
  float* attentive = (float*)((char*)bfQ + 32768);
  float* user_repr = (float*)((char*)attentive + 25600);
  float* e1buf     = user_repr + 128;
  float* e2buf     = e1buf + 64;
  float* fpart = (float*)relbf;   // overlays relbf (dead after gemm_kv_mfma); 8*118*50*18*4 = 3.4 MB < 15.36 MB
  char* U = (char*)(e2buf + 64);
  unsigned* pe_part = (unsigned*)U;
  unsigned* pn_part = pe_part + (size_t)3*NBKT*BCAP;
  unsigned short* e_slot = (unsigned short*)(pn_part + (size_t)3*NBKT*BCAP);
  unsigned short* xb     = e_slot + (size_t)3*E_*CAPE_;   // 60001 rows (last = zero row)
  unsigned short* Kb  = (unsigned short*)U;
  unsigned short* Vtg = Kb + (size_t)H_*NK_*16;

  // ---- zero bin counters via graph memset node (frees prep/binA dependency) ----
  hipMemsetAsync(gcnt_e, 0, 4096, stream);

  // ---- merged prep + binA (independent; overlap in one launch) ----
  Ptr3f xs = {{f32(0), f32(1), f32(2)}};
  prep_binA<<<BINA_B + PB_TOT, 256, 0, stream>>>(xs, xb, f32(12), f32(14), bfB, m_buf,
                                   f32(3), f32(10), f32(11), bfQ, f32(20), f32(21), e2buf,
                                   nodes, edges, pe_part, pn_part, gcnt_e, gcnt_n);

  // ---- binB e-side ----
  binB_e<<<dim3(NBKT, 3), 256, 0, stream>>>(pe_part, gcnt_e, cnt_all, e_slot);

  // ---- binB n-side overlapped with XCD-pinned group-per-edge gather ----
  egather_binbn<<<NBB + EGB, 256, 0, stream>>>(xb, cnt_all, e_slot, m_mean,
                                               pn_part, gcnt_n, cnt_all, n_slot);

  // ---- theta GEMM + node gather ----
  GemmB g;
  for (int mod=0; mod<3; mod++){
    g.A[mod] = m_mean + (size_t)mod*E_*D_;
    g.W[mod] = f32(4 + 2*mod);
    g.C[mod] = m_buf + (size_t)mod*E_*D_;
  }
  gemm_b<<<dim3((E_+63)/64, 3), 256, 0, stream>>>(g, E_);
  Ptr3f biases = {{f32(5), f32(7), f32(9)}};
  n_gather_g<<<dim3(N_/16, 3), 256, 0, stream>>>(m_buf, cnt_all, n_slot, biases, relbf);

  // ---- MHA ----
  gemm_kv_mfma<<<KVBLK, 256, 0, stream>>>(relbf, bfB, f32(13), f32(15), Kb, Vtg);
  flash3<<<dim3(NCH3, H_), 256, 0, stream>>>(Kb, Vtg, bfQ, fpart);
  merge_oproj_e1<<<C_, 512, 0, stream>>>(fpart, f32(16), f32(17), f32(18), f32(19),
                                         attentive, e1buf);

  // ---- fused tail + scores ----
  tail_scores<<<(NENT_+255)/256, 256, 0, stream>>>(attentive, f32(3), f32(20), f32(21),
                                                   e1buf, e2buf, f32(22), f32(23), (float*)d_out);
}

// Round 13
// 315.623 us; speedup vs baseline: 1.1297x; 1.0474x over previous
//
#include <hip/hip_runtime.h>
#include <hip/hip_bf16.h>

#define D_ 128
#define H_ 8
#define N_ 20000
#define NNZ_ 500000
#define E_ 5000
#define C_ 50
#define NENT_ 50000
#define NK_ (3*N_)
#define CAPE_ 192
#define CAPN_ 64
#define ENT_PB 4096
#define NBKT 157
#define BCAP 3648
#define ABLK 123
#define NCH3 118            // chunks per head, 512 keys each; 1 merged partial per chunk
#define KVBLK 235           // ceil(60000/256)
#define BINA_B (3*ABLK)     // 369 binA blocks, prefixed into prep_binA
#define NBB (3*NBKT)        // 471 binB n-side blocks, prefixed into egather kernel
#define EGB 3752

struct Ptr3f { const float* p[3]; };
struct Ptr3i { const int* p[3]; };
struct GemmB { const float* A[3]; const float* W[3]; unsigned short* C[3]; };

typedef short bf16x8 __attribute__((ext_vector_type(8)));
typedef float f32x4  __attribute__((ext_vector_type(4)));
typedef float f32x2  __attribute__((ext_vector_type(2)));

__device__ __forceinline__ unsigned short f2b(float f){
  unsigned u = __float_as_uint(f);
  u += 0x7FFFu + ((u>>16)&1u);
  return (unsigned short)(u>>16);
}
__device__ __forceinline__ unsigned pk2(float a, float b){
  return (unsigned)f2b(a) | ((unsigned)f2b(b) << 16);
}
__device__ __forceinline__ float blo(unsigned u){ return __uint_as_float(u<<16); }
__device__ __forceinline__ float bhi(unsigned u){ return __uint_as_float(u & 0xFFFF0000u); }

// one 32-row gather batch: 8 uint4 loads (4 rows x 16 lanes each), accumulate into f32x2 pairs.
// SREG holds PRE-SHIFTED byte offsets (idx<<8); SRCB is a char* base with dl*8 folded in.
#define GBATCH(SRCB, SREG, LBASE) { \
  uint4 uu[8]; \
  _Pragma("unroll") \
  for (int kk=0;kk<8;kk++){ \
    int off = __shfl(SREG, (LBASE) + 4*kk + rgrp); \
    uu[kk] = *(const uint4*)((SRCB) + off); \
  } \
  _Pragma("unroll") \
  for (int kk=0;kk<8;kk++){ \
    a01 += (f32x2){blo(uu[kk].x), bhi(uu[kk].x)}; \
    a23 += (f32x2){blo(uu[kk].y), bhi(uu[kk].y)}; \
    a45 += (f32x2){blo(uu[kk].z), bhi(uu[kk].z)}; \
    a67 += (f32x2){blo(uu[kk].w), bhi(uu[kk].w)}; \
  } }

// ---------------- merged prep + binA (independent stages share one launch) ----------------
#define PB_PACK 7500
#define PB_Z    7628
#define PB_Q    7629
#define PB_CTX  7693
#define PB_TOT  7743
__global__ __launch_bounds__(256) void prep_binA(Ptr3f xs, unsigned short* __restrict__ xb,
    const float* __restrict__ Wk, const float* __restrict__ Wv, unsigned short* __restrict__ bfB,
    unsigned short* __restrict__ mzero,
    const float* __restrict__ ctx, const float* __restrict__ Wq, const float* __restrict__ bq,
    unsigned short* __restrict__ bfQ,
    const float* __restrict__ a2, const float* __restrict__ b2, float* __restrict__ e2,
    Ptr3i nodes, Ptr3i edges,
    unsigned* __restrict__ pe_part, unsigned* __restrict__ pn_part,
    int* __restrict__ gcnt_e, int* __restrict__ gcnt_n)
{
  const int t = threadIdx.x;
  if (blockIdx.x < BINA_B){
    // ================= binA =================
    __shared__ unsigned lbin[ENT_PB];
    __shared__ int cnt[256], off[256];
    __shared__ int gbase[NBKT];
    __shared__ int wsum[4];
    const int mod = blockIdx.x / ABLK;
    const int xblk = blockIdx.x - mod*ABLK;
    const int* nd = nodes.p[mod];
    const int* ed = edges.p[mod];
    const int base = xblk * ENT_PB;
    const int lane = t & 63, w = t >> 6;

    int myn[16], mye[16], pos[16];
    #pragma unroll
    for (int k=0;k<16;k++){
      int i = base + t + k*256;
      if (i < NNZ_){ myn[k]=nd[i]; mye[k]=ed[i]; }
      else { myn[k]=-1; mye[k]=-1; }
    }

    cnt[t] = 0;
    __syncthreads();
    #pragma unroll
    for (int k=0;k<16;k++)
      if (mye[k] >= 0) pos[k] = atomicAdd(&cnt[mye[k]>>5], 1);
    __syncthreads();
    {
      int v = cnt[t], s = v;
      #pragma unroll
      for (int d=1; d<64; d<<=1){ int u=__shfl_up(s,d); if (lane>=d) s+=u; }
      if (lane==63) wsum[w]=s;
      __syncthreads();
      int wb=0;
      for (int i=0;i<w;i++) wb+=wsum[i];
      off[t] = wb + s - v;
      __syncthreads();
    }
    #pragma unroll
    for (int k=0;k<16;k++)
      if (mye[k] >= 0)
        lbin[off[mye[k]>>5] + pos[k]] = ((unsigned)mye[k] << 15) | (unsigned)myn[k];
    if (t < NBKT && cnt[t] > 0) gbase[t] = atomicAdd(&gcnt_e[mod*NBKT + t], cnt[t]);
    __syncthreads();
    {
      int total = off[255];
      unsigned* dstreg = pe_part + (size_t)mod*NBKT*BCAP;
      for (int i=t; i<total; i+=256){
        unsigned pk = lbin[i];
        int b = pk >> 20;
        int gp = gbase[b] + (i - off[b]);
        if (gp < BCAP) dstreg[(size_t)b*BCAP + gp] = pk;
      }
    }
    __syncthreads();

    cnt[t] = 0;
    __syncthreads();
    #pragma unroll
    for (int k=0;k<16;k++)
      if (myn[k] >= 0) pos[k] = atomicAdd(&cnt[myn[k]>>7], 1);
    __syncthreads();
    {
      int v = cnt[t], s = v;
      #pragma unroll
      for (int d=1; d<64; d<<=1){ int u=__shfl_up(s,d); if (lane>=d) s+=u; }
      if (lane==63) wsum[w]=s;
      __syncthreads();
      int wb=0;
      for (int i=0;i<w;i++) wb+=wsum[i];
      off[t] = wb + s - v;
      __syncthreads();
    }
    #pragma unroll
    for (int k=0;k<16;k++)
      if (myn[k] >= 0)
        lbin[off[myn[k]>>7] + pos[k]] = ((unsigned)myn[k] << 13) | (unsigned)mye[k];
    if (t < NBKT && cnt[t] > 0) gbase[t] = atomicAdd(&gcnt_n[mod*NBKT + t], cnt[t]);
    __syncthreads();
    {
      int total = off[255];
      unsigned* dstreg = pn_part + (size_t)mod*NBKT*BCAP;
      for (int i=t; i<total; i+=256){
        unsigned pk = lbin[i];
        int b = pk >> 20;
        int gp = gbase[b] + (i - off[b]);
        if (gp < BCAP) dstreg[(size_t)b*BCAP + gp] = pk;
      }
    }
    return;
  }

  // ================= prep =================
  int bid = blockIdx.x - BINA_B;
  if (bid < PB_PACK){
    int mod = bid / 2500, blk = bid - mod*2500;
    int i4 = blk*256 + t;
    float4 v = *(const float4*)(xs.p[mod] + (size_t)i4*4);
    ushort4 o; o.x=f2b(v.x); o.y=f2b(v.y); o.z=f2b(v.z); o.w=f2b(v.w);
    *(ushort4*)(xb + (size_t)mod*N_*D_ + (size_t)i4*4) = o;
  } else if (bid < PB_Z){
    int idx = (bid - PB_PACK)*256 + t;     // 32768
    int j  = idx & 7;
    int L  = (idx >> 3) & 63;
    int kb = (idx >> 9) & 3;
    int tt = idx >> 11;
    int k = kb*32 + (L>>4)*8 + j;
    int x = L & 15;
    float v = (tt < 8) ? Wk[(size_t)k*128 + tt*16 + x] : Wv[(size_t)k*128 + (tt-8)*16 + x];
    bfB[idx] = f2b(v);
  } else if (bid == PB_Z){
    if (t < 64)       ((unsigned*)(xb    + (size_t)60000*128))[t]    = 0u;   // zero gather row (e-side)
    else if (t < 128) ((unsigned*)(mzero + (size_t)15000*128))[t-64] = 0u;   // zero gather row (n-side)
  } else if (bid < PB_CTX){
    int idx = (bid - PB_Q)*256 + t;        // 16384
    int j  = idx & 7;
    int L  = (idx >> 3) & 63;
    int qt = (idx >> 9) & 3;
    int h  = idx >> 11;
    int k  = ((L>>4)&3)*8 + j;
    int q  = qt*16 + (L & 15);
    float val = 0.f;
    if (k < 16 && q < C_){
      const float* cr = ctx + (size_t)q*128;
      const float* wc = Wq + h*16 + k;
      float s0=0.f,s1=0.f,s2=0.f,s3=0.f;
      for (int d=0; d<128; d+=4){
        s0 = fmaf(cr[d],   wc[(size_t) d   *128], s0);
        s1 = fmaf(cr[d+1], wc[(size_t)(d+1)*128], s1);
        s2 = fmaf(cr[d+2], wc[(size_t)(d+2)*128], s2);
        s3 = fmaf(cr[d+3], wc[(size_t)(d+3)*128], s3);
      }
      val = 0.25f * (s0+s1+s2+s3 + bq[h*16+k]);
    }
    bfQ[idx] = f2b(val);
  } else {
    __shared__ float row[128];
    __shared__ float ps[128][2];
    __shared__ float red[2];
    int q = bid - PB_CTX;
    if (t < 128) row[t] = ctx[(size_t)q*128 + t];
    __syncthreads();
    int c = t & 127, half = t >> 7;
    float s = 0.f;
    int d0 = half*64;
    for (int d=d0; d<d0+64; d+=4){
      s = fmaf(row[d],   a2[(size_t) d   *128 + c], s);
      s = fmaf(row[d+1], a2[(size_t)(d+1)*128 + c], s);
      s = fmaf(row[d+2], a2[(size_t)(d+2)*128 + c], s);
      s = fmaf(row[d+3], a2[(size_t)(d+3)*128 + c], s);
    }
    ps[c][half] = s;
    __syncthreads();
    if (t < 128){
      float v = tanhf(ps[t][0] + ps[t][1]) * b2[t];
      #pragma unroll
      for (int k=32; k>=1; k>>=1) v += __shfl_xor(v, k);
      if ((t & 63) == 0) red[t>>6] = v;
    }
    __syncthreads();
    if (t == 0) e2[q] = red[0] + red[1];
  }
}

// ---------------- binB e-side only (dummy-padded slot rows) ----------------
__global__ __launch_bounds__(256) void binB_e(const unsigned* __restrict__ pe_part,
    const int* __restrict__ gcnt_e, int* __restrict__ cnt_all,
    unsigned short* __restrict__ e_slot)
{
  __shared__ unsigned short ls[32*CAPE_];
  __shared__ int lc[32];
  const int mod = blockIdx.y, b = blockIdx.x, t = threadIdx.x;
  {
    unsigned short dmy = (unsigned short)(60000 - mod*20000);
    unsigned dd = (unsigned)dmy * 0x10001u;
    unsigned* lsu32 = (unsigned*)ls;
    for (int i=t; i<32*CAPE_/2; i+=256) lsu32[i] = dd;
  }
  if (t < 32) lc[t] = 0;
  __syncthreads();
  int cnt = gcnt_e[mod*NBKT + b];
  if (cnt > BCAP) cnt = BCAP;
  const unsigned* src = pe_part + ((size_t)mod*NBKT + b)*BCAP;
  for (int i=t; i<cnt; i+=256){
    unsigned pk = src[i];
    int el = (pk >> 15) - b*32;
    int n  = pk & 0x7FFF;
    int p = atomicAdd(&lc[el], 1);
    if (p < CAPE_) ls[el*CAPE_ + p] = (unsigned short)n;
  }
  __syncthreads();
  int rows = E_ - b*32; if (rows > 32) rows = 32;
  if (t < rows) cnt_all[mod*(E_+N_) + b*32 + t] = lc[t];
  const unsigned* lsu = (const unsigned*)ls;
  unsigned* dst = (unsigned*)(e_slot + ((size_t)mod*E_ + b*32)*CAPE_);
  int tot = rows*CAPE_/2;
  for (int i=t; i<tot; i+=256) dst[i] = lsu[i];
}

// ---------------- merged binB n-side + XCD-pinned edge gather ----------------
__global__ __launch_bounds__(256) void egather_binbn(const unsigned short* __restrict__ xb,
    const int* __restrict__ cnt_all, const unsigned short* __restrict__ e_slot,
    float* __restrict__ m_mean,
    const unsigned* __restrict__ pn_part, const int* __restrict__ gcnt_n,
    int* __restrict__ cnt_all_w, unsigned short* __restrict__ n_slot)
{
  __shared__ unsigned short ls[128*CAPN_];
  __shared__ int lc[128];
  const int t = threadIdx.x;
  if (blockIdx.x < NBB){
    // ================= binB n-side =================
    const int mod = blockIdx.x / NBKT, b = blockIdx.x - mod*NBKT;
    {
      unsigned short dmy = (unsigned short)(15000 - mod*5000);
      unsigned dd = (unsigned)dmy * 0x10001u;
      unsigned* lsu32 = (unsigned*)ls;
      for (int i=t; i<128*CAPN_/2; i+=256) lsu32[i] = dd;
    }
    if (t < 128) lc[t] = 0;
    __syncthreads();
    int cnt = gcnt_n[mod*NBKT + b];
    if (cnt > BCAP) cnt = BCAP;
    const unsigned* src = pn_part + ((size_t)mod*NBKT + b)*BCAP;
    for (int i=t; i<cnt; i+=256){
      unsigned pk = src[i];
      int nl = (pk >> 13) - b*128;
      int e  = pk & 0x1FFF;
      int p = atomicAdd(&lc[nl], 1);
      if (p < CAPN_) ls[nl*CAPN_ + p] = (unsigned short)e;
    }
    __syncthreads();
    int rows = N_ - b*128; if (rows > 128) rows = 128;
    if (t < rows) cnt_all_w[mod*(E_+N_) + E_ + b*128 + t] = lc[t];
    const unsigned* lsu = (const unsigned*)ls;
    unsigned* dst = (unsigned*)(n_slot + ((size_t)mod*N_ + b*128)*CAPN_);
    int tot = rows*CAPN_/2;
    for (int i=t; i<tot; i+=256) dst[i] = lsu[i];
    return;
  }

  // ================= e_gather =================
  const int bb = blockIdx.x - NBB;
  const int x = bb & 7, k = bb >> 3;          // k in [0,469)
  int mod, r;
  if (x < 6){
    mod = x / 3;
    int li = x - mod*3;
    int c = 417 - (li == 2);
    if (k < c){
      r = k*3 + li;
    } else {
      int hg = 52*x + (x >= 3) + (k - c);     // helper index into mod2 tail
      mod = 2; r = 938 + hg;
      if (r >= E_/4) return;                  // 2 slack blocks
    }
  } else {
    mod = 2; r = k*2 + (x - 6);               // r < 938
  }
  const int w = t >> 6, lane = t & 63;
  const int rgrp = lane >> 4, dl = lane & 15;
  const int e = r*4 + w;
  const char* xt8 = (const char*)(xb + (size_t)mod*N_*D_) + dl*8*2;
  int cnt = cnt_all[mod*(E_+N_) + e];
  int c2 = (cnt < CAPE_) ? cnt : CAPE_;
  int c2p = (c2 + 31) & ~31;                  // <= 192, wave-uniform
  const unsigned short* slot = e_slot + ((size_t)mod*E_ + e)*CAPE_;
  int sv0 = ((int)slot[lane]) << 8;
  int sv1 = ((int)slot[64 + lane]) << 8;
  int sv2 = ((int)slot[128 + lane]) << 8;
  f32x2 a01={0.f,0.f}, a23={0.f,0.f}, a45={0.f,0.f}, a67={0.f,0.f};

  if (c2p > 0)   GBATCH(xt8, sv0, 0);
  if (c2p > 32)  GBATCH(xt8, sv0, 32);
  if (c2p > 64)  GBATCH(xt8, sv1, 0);
  if (c2p > 96)  GBATCH(xt8, sv1, 32);
  if (c2p > 128) GBATCH(xt8, sv2, 0);
  if (c2p > 160) GBATCH(xt8, sv2, 32);

  float a0=a01.x, a1=a01.y, a2=a23.x, a3=a23.y, a4=a45.x, a5=a45.y, a6=a67.x, a7=a67.y;
  #pragma unroll
  for (int s=16; s<=32; s<<=1){
    a0 += __shfl_xor(a0, s); a1 += __shfl_xor(a1, s);
    a2 += __shfl_xor(a2, s); a3 += __shfl_xor(a3, s);
    a4 += __shfl_xor(a4, s); a5 += __shfl_xor(a5, s);
    a6 += __shfl_xor(a6, s); a7 += __shfl_xor(a7, s);
  }
  if (rgrp == 0){
    float inv = 1.f / fmaxf((float)cnt, 1.f);
    float* dst = m_mean + ((size_t)mod*E_ + e)*128 + dl*8;
    float4 o1; o1.x=a0*inv; o1.y=a1*inv; o1.z=a2*inv; o1.w=a3*inv;
    float4 o2; o2.x=a4*inv; o2.y=a5*inv; o2.z=a6*inv; o2.w=a7*inv;
    *(float4*)dst = o1;
    *(float4*)(dst + 4) = o2;
  }
}

// ---------------- batched theta GEMM ----------------
__global__ __launch_bounds__(256) void gemm_b(GemmB g, int M)
{
  const float* A = g.A[blockIdx.y];
  const float* W = g.W[blockIdx.y];
  unsigned short* Cout = g.C[blockIdx.y];
  __shared__ float As[64][33];
  __shared__ float Ws[32][128];
  const int t  = threadIdx.x;
  const int br = blockIdx.x * 64;
  const int r0 = (t >> 5) * 8;
  const int c0 = (t & 31) * 4;
  const int lr = t >> 2;
  const int lk = (t & 3) * 8;
  const int wk = t >> 5;

  float acc[8][4];
  #pragma unroll
  for (int i=0;i<8;i++){ acc[i][0]=0.f; acc[i][1]=0.f; acc[i][2]=0.f; acc[i][3]=0.f; }

  for (int kb=0; kb<128; kb+=32){
    float av[8];
    const int grow = br + lr;
    if (grow < M){
      const float* p = A + (size_t)grow*128 + kb + lk;
      float4 a = ((const float4*)p)[0], b = ((const float4*)p)[1];
      av[0]=a.x;av[1]=a.y;av[2]=a.z;av[3]=a.w;av[4]=b.x;av[5]=b.y;av[6]=b.z;av[7]=b.w;
    } else {
      #pragma unroll
      for (int j=0;j<8;j++) av[j]=0.f;
    }
    float4 wv4[4];
    #pragma unroll
    for (int kk=0;kk<4;kk++) wv4[kk] = *(const float4*)&W[(size_t)(kb + wk + kk*8)*128 + c0];

    __syncthreads();
    #pragma unroll
    for (int j=0;j<8;j++) As[lr][lk+j] = av[j];
    #pragma unroll
    for (int kk=0;kk<4;kk++) *(float4*)&Ws[wk + kk*8][c0] = wv4[kk];
    __syncthreads();

    #pragma unroll
    for (int k=0;k<32;k++){
      float4 wv = *(const float4*)&Ws[k][c0];
      #pragma unroll
      for (int i=0;i<8;i++){
        float a = As[r0+i][k];
        acc[i][0] = fmaf(a, wv.x, acc[i][0]);
        acc[i][1] = fmaf(a, wv.y, acc[i][1]);
        acc[i][2] = fmaf(a, wv.z, acc[i][2]);
        acc[i][3] = fmaf(a, wv.w, acc[i][3]);
      }
    }
  }

  #pragma unroll
  for (int i=0;i<8;i++){
    int gr = br + r0 + i;
    if (gr < M){
      ushort4 o;
      o.x=f2b(acc[i][0]); o.y=f2b(acc[i][1]); o.z=f2b(acc[i][2]); o.w=f2b(acc[i][3]);
      *(ushort4*)(Cout + (size_t)gr*128 + c0) = o;
    }
  }
}

// ---------------- group-per-node gather-mean + bias -> bf16 related ----------------
// 16-lane group owns one node: lane dl owns dims dl*8..dl*8+7 end-to-end.
// NO cross-lane reduction, NO bpermute: slot indices arrive via one group-uniform
// uint4 load per 8 members (slot rows dummy-padded by binB -> tail adds 0).
__global__ __launch_bounds__(256) void n_gather_g(const unsigned short* __restrict__ m_buf,
    const int* __restrict__ cnt_all, const unsigned short* __restrict__ n_slot,
    Ptr3f biases, unsigned short* __restrict__ relbf)
{
  const int mod = blockIdx.y;
  const int t = threadIdx.x, w = t >> 6, lane = t & 63;
  const int g = lane >> 4, dl = lane & 15;
  const int n = blockIdx.x*16 + w*4 + g;
  const char* mb = (const char*)(m_buf + (size_t)mod*E_*D_) + dl*16;
  int cnt = cnt_all[mod*(E_+N_) + E_ + n];
  int c2 = (cnt < CAPN_) ? cnt : CAPN_;
  // wave-uniform loop bound: max c2 over the wave's 4 groups (only LDS ops in kernel)
  int m = c2;
  m = max(m, __shfl_xor(m, 16));
  m = max(m, __shfl_xor(m, 32));
  int m8 = (m + 7) & ~7;                     // <= 64
  const unsigned short* slot = n_slot + ((size_t)mod*N_ + n)*CAPN_;
  f32x2 a01={0.f,0.f}, a23={0.f,0.f}, a45={0.f,0.f}, a67={0.f,0.f};

  for (int j=0; j<m8; j+=8){
    uint4 sv = *(const uint4*)(slot + j);    // 8 member indices, group-uniform
    int o0 = (int)(sv.x & 0xFFFFu) << 8, o1 = (int)(sv.x >> 16) << 8;
    int o2 = (int)(sv.y & 0xFFFFu) << 8, o3 = (int)(sv.y >> 16) << 8;
    int o4 = (int)(sv.z & 0xFFFFu) << 8, o5 = (int)(sv.z >> 16) << 8;
    int o6 = (int)(sv.w & 0xFFFFu) << 8, o7 = (int)(sv.w >> 16) << 8;
    uint4 u0 = *(const uint4*)(mb + o0);
    uint4 u1 = *(const uint4*)(mb + o1);
    uint4 u2 = *(const uint4*)(mb + o2);
    uint4 u3 = *(const uint4*)(mb + o3);
    uint4 u4 = *(const uint4*)(mb + o4);
    uint4 u5 = *(const uint4*)(mb + o5);
    uint4 u6 = *(const uint4*)(mb + o6);
    uint4 u7 = *(const uint4*)(mb + o7);
    a01 += (f32x2){blo(u0.x), bhi(u0.x)}; a23 += (f32x2){blo(u0.y), bhi(u0.y)};
    a45 += (f32x2){blo(u0.z), bhi(u0.z)}; a67 += (f32x2){blo(u0.w), bhi(u0.w)};
    a01 += (f32x2){blo(u1.x), bhi(u1.x)}; a23 += (f32x2){blo(u1.y), bhi(u1.y)};
    a45 += (f32x2){blo(u1.z), bhi(u1.z)}; a67 += (f32x2){blo(u1.w), bhi(u1.w)};
    a01 += (f32x2){blo(u2.x), bhi(u2.x)}; a23 += (f32x2){blo(u2.y), bhi(u2.y)};
    a45 += (f32x2){blo(u2.z), bhi(u2.z)}; a67 += (f32x2){blo(u2.w), bhi(u2.w)};
    a01 += (f32x2){blo(u3.x), bhi(u3.x)}; a23 += (f32x2){blo(u3.y), bhi(u3.y)};
    a45 += (f32x2){blo(u3.z), bhi(u3.z)}; a67 += (f32x2){blo(u3.w), bhi(u3.w)};
    a01 += (f32x2){blo(u4.x), bhi(u4.x)}; a23 += (f32x2){blo(u4.y), bhi(u4.y)};
    a45 += (f32x2){blo(u4.z), bhi(u4.z)}; a67 += (f32x2){blo(u4.w), bhi(u4.w)};
    a01 += (f32x2){blo(u5.x), bhi(u5.x)}; a23 += (f32x2){blo(u5.y), bhi(u5.y)};
    a45 += (f32x2){blo(u5.z), bhi(u5.z)}; a67 += (f32x2){blo(u5.w), bhi(u5.w)};
    a01 += (f32x2){blo(u6.x), bhi(u6.x)}; a23 += (f32x2){blo(u6.y), bhi(u6.y)};
    a45 += (f32x2){blo(u6.z), bhi(u6.z)}; a67 += (f32x2){blo(u6.w), bhi(u6.w)};
    a01 += (f32x2){blo(u7.x), bhi(u7.x)}; a23 += (f32x2){blo(u7.y), bhi(u7.y)};
    a45 += (f32x2){blo(u7.z), bhi(u7.z)}; a67 += (f32x2){blo(u7.w), bhi(u7.w)};
  }

  float inv = 1.f / fmaxf((float)cnt, 1.f);
  const float* bs = biases.p[mod] + dl*8;
  uint4 o;
  o.x = pk2(a01.x*inv + bs[0], a01.y*inv + bs[1]);
  o.y = pk2(a23.x*inv + bs[2], a23.y*inv + bs[3]);
  o.z = pk2(a45.x*inv + bs[4], a45.y*inv + bs[5]);
  o.w = pk2(a67.x*inv + bs[6], a67.y*inv + bs[7]);
  *(uint4*)(relbf + ((size_t)mod*N_ + n)*128 + dl*8) = o;
}

// ---------------- MFMA KV GEMM v2: B from L2, V staged in LDS for coalesced writes ----------------
__global__ __launch_bounds__(256) void gemm_kv_mfma(const unsigned short* __restrict__ relbf,
    const unsigned short* __restrict__ bfB, const float* __restrict__ bk,
    const float* __restrict__ bv, unsigned short* __restrict__ Kb,
    unsigned short* __restrict__ Vtg)
{
  __shared__ unsigned short Vs[128][72];   // 18.4 KB, 144B rows (16B-aligned)
  const int t = threadIdx.x, w = t >> 6, L = t & 63;
  const int m = L & 15, quad = L >> 4, x = m;
  const int rowbase = blockIdx.x*256;

  for (int g = 0; g < 4; g++){
    const int j0 = rowbase + g*64 + w*16;

    bf16x8 a[4];
    {
      int row = j0 + m;
      int rowc = (row < NK_) ? row : (NK_-1);
      #pragma unroll
      for (int kb=0; kb<4; kb++)
        a[kb] = *(const bf16x8*)(relbf + (size_t)rowc*128 + kb*32 + quad*8);
    }

    f32x4 acc[16];
    #pragma unroll
    for (int tt=0; tt<16; tt++) acc[tt] = (f32x4){0.f,0.f,0.f,0.f};

    #pragma unroll
    for (int kb=0; kb<4; kb++){
      #pragma unroll
      for (int tt=0; tt<16; tt++){
        bf16x8 b = *(const bf16x8*)(bfB + (((tt*4 + kb)*64 + L) << 3));
        acc[tt] = __builtin_amdgcn_mfma_f32_16x16x32_bf16(a[kb], b, acc[tt], 0, 0, 0);
      }
    }

    // ---- K: direct stores (already 32B-contiguous across x lanes) ----
    #pragma unroll
    for (int tt=0; tt<8; tt++){
      float bias = bk[tt*16 + x];
      unsigned p0, p1;
      asm("v_cvt_pk_bf16_f32 %0, %1, %2" : "=v"(p0) : "v"(acc[tt][0]+bias), "v"(acc[tt][1]+bias));
      asm("v_cvt_pk_bf16_f32 %0, %1, %2" : "=v"(p1) : "v"(acc[tt][2]+bias), "v"(acc[tt][3]+bias));
      int jrb = j0 + quad*4;
      if (jrb + 3 < NK_){
        Kb[(((size_t)tt*NK_ + jrb    ) << 4) + x] = (unsigned short)p0;
        Kb[(((size_t)tt*NK_ + jrb + 1) << 4) + x] = (unsigned short)(p0 >> 16);
        Kb[(((size_t)tt*NK_ + jrb + 2) << 4) + x] = (unsigned short)p1;
        Kb[(((size_t)tt*NK_ + jrb + 3) << 4) + x] = (unsigned short)(p1 >> 16);
      } else {
        if (jrb     < NK_) Kb[(((size_t)tt*NK_ + jrb    ) << 4) + x] = (unsigned short)p0;
        if (jrb + 1 < NK_) Kb[(((size_t)tt*NK_ + jrb + 1) << 4) + x] = (unsigned short)(p0 >> 16);
        if (jrb + 2 < NK_) Kb[(((size_t)tt*NK_ + jrb + 2) << 4) + x] = (unsigned short)p1;
        if (jrb + 3 < NK_) Kb[(((size_t)tt*NK_ + jrb + 3) << 4) + x] = (unsigned short)(p1 >> 16);
      }
    }

    // ---- V: stage to LDS (col-contiguous matches register layout) ----
    #pragma unroll
    for (int tt=8; tt<16; tt++){
      int h = tt - 8;
      float bias = bv[h*16 + x];
      unsigned p0, p1;
      asm("v_cvt_pk_bf16_f32 %0, %1, %2" : "=v"(p0) : "v"(acc[tt][0]+bias), "v"(acc[tt][1]+bias));
      asm("v_cvt_pk_bf16_f32 %0, %1, %2" : "=v"(p1) : "v"(acc[tt][2]+bias), "v"(acc[tt][3]+bias));
      int col = w*16 + quad*4;
      *(unsigned*)&Vs[h*16 + x][col]     = p0;
      *(unsigned*)&Vs[h*16 + x][col + 2] = p1;
    }
    __syncthreads();

    // ---- V flush: 128 rows x 64 cols, 64B contiguous per thread ----
    {
      int row = t >> 1, half = t & 1;
      int c0 = half*32;
      int jr0 = rowbase + g*64 + c0;
      const unsigned short* src = &Vs[row][c0];
      unsigned short* dstp = Vtg + (size_t)row*NK_ + jr0;
      if (jr0 + 31 < NK_){
        ((uint4*)dstp)[0] = ((const uint4*)src)[0];
        ((uint4*)dstp)[1] = ((const uint4*)src)[1];
        ((uint4*)dstp)[2] = ((const uint4*)src)[2];
        ((uint4*)dstp)[3] = ((const uint4*)src)[3];
      } else {
        for (int c=0; c<32; c++) if (jr0 + c < NK_) dstp[c] = src[c];
      }
    }
    __syncthreads();
  }
}

// ---------------- MFMA flash with in-block 4-wave merge (512-key chunks for occupancy) ----------------
__global__ __launch_bounds__(256) void flash3(const unsigned short* __restrict__ Kb,
    const unsigned short* __restrict__ Vtg, const unsigned short* __restrict__ bfQ,
    float* __restrict__ part)
{
  __shared__ unsigned short P_lds[4][64][40];
  __shared__ float mbuf[4][64][18];
  const int c = blockIdx.x, h = blockIdx.y;
  const int t = threadIdx.x, w = t >> 6, L = t & 63;
  const int n = L & 15, quad = L >> 4;

  bf16x8 qb[4];
  #pragma unroll
  for (int qt=0; qt<4; qt++)
    qb[qt] = *(const bf16x8*)(bfQ + (((h*4 + qt)*64 + L) << 3));

  float Mc[4], Lc[4];
  f32x4 accq[4];
  #pragma unroll
  for (int qt=0; qt<4; qt++){ Mc[qt] = -INFINITY; Lc[qt] = 0.f; accq[qt] = (f32x4){0.f,0.f,0.f,0.f}; }

  const int base = c*512 + w*128;
  unsigned* Pw = (unsigned*)&P_lds[w][0][0];

  for (int tile=0; tile<4; tile++){
    const int j0 = base + tile*32;
    const bool dead = (j0 >= NK_);

    bf16x8 a0 = (bf16x8){0,0,0,0,0,0,0,0};
    bf16x8 a1 = a0;
    if (quad < 2){
      int k0 = j0 + n;      if (k0 > NK_-1) k0 = NK_-1;
      int k1 = j0 + 16 + n; if (k1 > NK_-1) k1 = NK_-1;
      a0 = *(const bf16x8*)(Kb + (((size_t)h*NK_ + k0) << 4) + quad*8);
      a1 = *(const bf16x8*)(Kb + (((size_t)h*NK_ + k1) << 4) + quad*8);
    }
    f32x4 s0[4], s1[4];
    #pragma unroll
    for (int qt=0; qt<4; qt++){
      s0[qt] = __builtin_amdgcn_mfma_f32_16x16x32_bf16(a0, qb[qt], (f32x4){0.f,0.f,0.f,0.f}, 0,0,0);
      s1[qt] = __builtin_amdgcn_mfma_f32_16x16x32_bf16(a1, qb[qt], (f32x4){0.f,0.f,0.f,0.f}, 0,0,0);
    }

    #pragma unroll
    for (int qt=0; qt<4; qt++){
      float mt = s0[qt][0];
      mt = fmaxf(mt, s0[qt][1]); mt = fmaxf(mt, s0[qt][2]); mt = fmaxf(mt, s0[qt][3]);
      mt = fmaxf(mt, s1[qt][0]); mt = fmaxf(mt, s1[qt][1]);
      mt = fmaxf(mt, s1[qt][2]); mt = fmaxf(mt, s1[qt][3]);
      mt = fmaxf(mt, __shfl_xor(mt, 16));
      mt = fmaxf(mt, __shfl_xor(mt, 32));
      float Mn = fmaxf(Mc[qt], mt);
      float corr = __expf(Mc[qt] - Mn);
      Mc[qt] = Mn;
      float p0[4], p1[4];
      #pragma unroll
      for (int r=0;r<4;r++){
        p0[r] = __expf(s0[qt][r] - Mn);
        p1[r] = __expf(s1[qt][r] - Mn);
      }
      if (dead){
        #pragma unroll
        for (int r=0;r<4;r++){ p0[r]=0.f; p1[r]=0.f; }
      }
      float lt = p0[0]+p0[1]+p0[2]+p0[3]+p1[0]+p1[1]+p1[2]+p1[3];
      lt += __shfl_xor(lt, 16);
      lt += __shfl_xor(lt, 32);
      Lc[qt] = Lc[qt]*corr + lt;
      int rb = (qt*16 + n)*20;
      Pw[rb + quad*2]     = pk2(p0[0], p0[1]);
      Pw[rb + quad*2 + 1] = pk2(p0[2], p0[3]);
      Pw[rb + 8 + quad*2]     = pk2(p1[0], p1[1]);
      Pw[rb + 8 + quad*2 + 1] = pk2(p1[2], p1[3]);
      #pragma unroll
      for (int r=0;r<4;r++){
        float cr = __shfl(corr, quad*4 + r);
        accq[qt][r] *= cr;
      }
    }
    __syncthreads();

    bf16x8 bv_;
    {
      int va = j0 + quad*8; if (va > NK_-8) va = NK_-8;
      bv_ = *(const bf16x8*)(Vtg + ((size_t)(h*16 + n))*NK_ + va);
    }
    #pragma unroll
    for (int qt=0; qt<4; qt++){
      bf16x8 pa = *(const bf16x8*)&P_lds[w][qt*16 + n][quad*8];
      accq[qt] = __builtin_amdgcn_mfma_f32_16x16x32_bf16(pa, bv_, accq[qt], 0,0,0);
    }
    __syncthreads();
  }

  #pragma unroll
  for (int qt=0; qt<4; qt++){
    #pragma unroll
    for (int r=0; r<4; r++)
      mbuf[w][qt*16 + quad*4 + r][2 + n] = accq[qt][r];
    if (quad == 0){
      mbuf[w][qt*16 + n][0] = Mc[qt];
      mbuf[w][qt*16 + n][1] = Lc[qt];
    }
  }
  __syncthreads();
  if (t < C_){
    float M = mbuf[0][t][0], Lm = mbuf[0][t][1];
    float A[16];
    #pragma unroll
    for (int i=0;i<16;i++) A[i] = mbuf[0][t][2+i];
    #pragma unroll
    for (int ww=1; ww<4; ww++){
      float pm = mbuf[ww][t][0], pl = mbuf[ww][t][1];
      if (pl > 0.f){
        float mn = fmaxf(M, pm);
        float c1 = __expf(M - mn), c2 = __expf(pm - mn);
        Lm = Lm*c1 + pl*c2;
        #pragma unroll
        for (int i=0;i<16;i++) A[i] = A[i]*c1 + mbuf[ww][t][2+i]*c2;
        M = mn;
      }
    }
    float* pp = part + ((size_t)(h*NCH3 + c)*C_ + t)*18;
    pp[0] = M; pp[1] = Lm;
    #pragma unroll
    for (int i=0;i<16;i++) pp[2+i] = A[i];
  }
}

// ---------------- wave-parallel flash-merge + O-projection + e1 row ----------------
__global__ __launch_bounds__(512) void merge_oproj_e1(const float* __restrict__ part,
    const float* __restrict__ Wo, const float* __restrict__ bo,
    const float* __restrict__ a1, const float* __restrict__ b1,
    float* __restrict__ attentive, float* __restrict__ e1)
{
  __shared__ float row[128];
  __shared__ float ps[128][4];
  __shared__ float orow[128];
  __shared__ float red[2];
  const int q = blockIdx.x, t = threadIdx.x;
  const int h = t >> 6, lane = t & 63;

  // ---- stage A: wave h merges NCH3 chunk partials for (h, q) ----
  {
    float M = -1e30f, L = 0.f;
    float A[16];
    #pragma unroll
    for (int i=0;i<16;i++) A[i] = 0.f;

    #pragma unroll
    for (int cc=0; cc<2; cc++){
      int c = lane + cc*64;
      if (c < NCH3){
        const float* p = part + ((size_t)(h*NCH3 + c)*C_ + q)*18;
        float pm = p[0], pl = p[1];
        if (pl > 0.f){
          float Mn = fmaxf(M, pm);
          float w1 = __expf(M - Mn), w2 = __expf(pm - Mn);
          L = L*w1 + pl*w2;
          #pragma unroll
          for (int i=0;i<16;i++) A[i] = fmaf(A[i], w1, p[2+i]*w2);
          M = Mn;
        }
      }
    }
    // 6-round butterfly merge across the wave
    #pragma unroll
    for (int d=32; d>=1; d>>=1){
      float pm = __shfl_xor(M, d);
      float pl = __shfl_xor(L, d);
      float Ao[16];
      #pragma unroll
      for (int i=0;i<16;i++) Ao[i] = __shfl_xor(A[i], d);
      float Mn = fmaxf(M, pm);
      float w1 = __expf(M - Mn), w2 = __expf(pm - Mn);
      L = L*w1 + pl*w2;
      #pragma unroll
      for (int i=0;i<16;i++) A[i] = fmaf(A[i], w1, Ao[i]*w2);
      M = Mn;
    }
    if (lane == 0){
      float invL = 1.f / L;
      #pragma unroll
      for (int i=0;i<16;i++) row[h*16 + i] = A[i]*invL;
    }
  }
  __syncthreads();

  // ---- stage B: O-projection (4-way d-split over 512 threads) ----
  const int c = t & 127, seg = t >> 7;
  {
    float s = 0.f;
    int d0 = seg*32;
    for (int d=d0; d<d0+32; d+=4){
      s = fmaf(row[d],   Wo[(size_t) d   *128 + c], s);
      s = fmaf(row[d+1], Wo[(size_t)(d+1)*128 + c], s);
      s = fmaf(row[d+2], Wo[(size_t)(d+2)*128 + c], s);
      s = fmaf(row[d+3], Wo[(size_t)(d+3)*128 + c], s);
    }
    ps[c][seg] = s;
  }
  __syncthreads();
  if (t < 128){
    float o = ps[t][0]+ps[t][1]+ps[t][2]+ps[t][3] + bo[t];
    attentive[(size_t)q*128 + t] = o;
    orow[t] = o;
  }
  __syncthreads();
  // ---- e1 row: tanh(orow @ a1) @ b1 ----
  {
    float s = 0.f;
    int d0 = seg*32;
    for (int d=d0; d<d0+32; d+=4){
      s = fmaf(orow[d],   a1[(size_t) d   *128 + c], s);
      s = fmaf(orow[d+1], a1[(size_t)(d+1)*128 + c], s);
      s = fmaf(orow[d+2], a1[(size_t)(d+2)*128 + c], s);
      s = fmaf(orow[d+3], a1[(size_t)(d+3)*128 + c], s);
    }
    ps[c][seg] = s;
  }
  __syncthreads();
  if (t < 128){
    float v = tanhf(ps[t][0]+ps[t][1]+ps[t][2]+ps[t][3]) * b1[t];
    #pragma unroll
    for (int k=32; k>=1; k>>=1) v += __shfl_xor(v, k);
    if ((t & 63) == 0) red[t>>6] = v;
  }
  __syncthreads();
  if (t == 0) e1[q] = red[0] + red[1];
}

// ---------------- fused tail + scores ----------------
__global__ __launch_bounds__(256) void tail_scores(const float* __restrict__ attentive,
    const float* __restrict__ ctx, const float* __restrict__ a2, const float* __restrict__ b2,
    const float* __restrict__ e1, const float* __restrict__ e2,
    const float* __restrict__ recW, const float* __restrict__ recb, float* __restrict__ out)
{
  __shared__ float p[64];
  __shared__ float u[128];
  __shared__ float red[2];
  __shared__ float p2[64];
  __shared__ float ur[128];
  const int t = threadIdx.x;

  if (t == 0){
    float mx=-INFINITY;
    for (int i=0;i<C_;i++) mx=fmaxf(mx,e1[i]);
    float ss=0.f;
    for (int i=0;i<C_;i++){ p[i]=__expf(e1[i]-mx); ss+=p[i]; }
    float inv=1.f/ss;
    for (int i=0;i<C_;i++) p[i]*=inv;
  }
  __syncthreads();
  if (t < 128){
    float s=0.f;
    for (int r=0;r<C_;r++) s = fmaf(p[r], attentive[(size_t)r*128 + t], s);
    u[t] = s;
  }
  __syncthreads();
  if (t < 128){
    float s0=0.f,s1=0.f,s2=0.f,s3=0.f;
    for (int d=0; d<128; d+=4){
      s0 = fmaf(u[d],   a2[(size_t) d   *128 + t], s0);
      s1 = fmaf(u[d+1], a2[(size_t)(d+1)*128 + t], s1);
      s2 = fmaf(u[d+2], a2[(size_t)(d+2)*128 + t], s2);
      s3 = fmaf(u[d+3], a2[(size_t)(d+3)*128 + t], s3);
    }
    float v = tanhf(s0+s1+s2+s3) * b2[t];
    #pragma unroll
    for (int k=32; k>=1; k>>=1) v += __shfl_xor(v, k);
    if ((t & 63) == 0) red[t>>6] = v;
  }
  __syncthreads();
  if (t == 0){
    float elast = red[0] + red[1];
    float mx=elast;
    for (int i=0;i<C_;i++) mx=fmaxf(mx,e2[i]);
    float ss=0.f;
    for (int i=0;i<C_;i++){ p2[i]=__expf(e2[i]-mx); ss+=p2[i]; }
    float pl = __expf(elast-mx); ss += pl;
    float inv=1.f/ss;
    for (int i=0;i<C_;i++) p2[i]*=inv;
    p2[C_] = pl*inv;
  }
  __syncthreads();
  if (t < 128){
    float s=0.f;
    for (int r=0;r<C_;r++) s = fmaf(p2[r], ctx[(size_t)r*128 + t], s);
    s = fmaf(p2[C_], u[t], s);
    ur[t] = s;
  }
  __syncthreads();
  int j = blockIdx.x*256 + t;
  if (j < NENT_){
    float s0=0.f,s1=0.f,s2=0.f,s3=0.f;
    for (int d=0; d<128; d+=4){
      s0 = fmaf(ur[d],   recW[(size_t) d   *NENT_ + j], s0);
      s1 = fmaf(ur[d+1], recW[(size_t)(d+1)*NENT_ + j], s1);
      s2 = fmaf(ur[d+2], recW[(size_t)(d+2)*NENT_ + j], s2);
      s3 = fmaf(ur[d+3], recW[(size_t)(d+3)*NENT_ + j], s3);
    }
    out[j] = s0+s1+s2+s3 + recb[j];
  }
}

// ---------------- launcher ----------------
extern "C" void kernel_launch(void* const* d_in, const int* in_sizes, int n_in,
                              void* d_out, int out_size, void* d_ws, size_t ws_size,
                              hipStream_t stream)
{
  auto f32 = [&](int i){ return (const float*)d_in[i]; };
  Ptr3i nodes = {{(const int*)d_in[24], (const int*)d_in[26], (const int*)d_in[28]}};
  Ptr3i edges = {{(const int*)d_in[25], (const int*)d_in[27], (const int*)d_in[29]}};

  // ---- workspace layout (~70 MB) ----
  char* base = (char*)d_ws;
  int*   cnt_all = (int*)base;
  int*   gcnt_e  = (int*)(base + 300064);
  int*   gcnt_n  = gcnt_e + NBKT*3;
  unsigned short* n_slot = (unsigned short*)(base + 300064 + 4096);
  float* m_mean  = (float*)((char*)n_slot + 7680000);
  unsigned short* m_buf = (unsigned short*)((char*)m_mean + 7680000);
  unsigned short* relbf = (unsigned short*)((char*)m_buf + 3840256);   // m_buf has +1 zero row (idx 15000)
  unsigned short* bfB   = (unsigned short*)((char*)relbf + 15360000);
  unsigned short* bfQ   = (unsigned short*)((char*)bfB + 65536);
  float* attentive = (float*)((char*)bfQ + 32768);
  float* user_repr = (float*)((char*)attentive + 25600);
  float* e1buf     = user_repr + 128;
  float* e2buf     = e1buf + 64;
  float* fpart = (float*)relbf;   // overlays relbf (dead after gemm_kv_mfma); 8*118*50*18*4 = 3.4 MB < 15.36 MB
  char* U = (char*)(e2buf + 64);
  unsigned* pe_part = (unsigned*)U;
  unsigned* pn_part = pe_part + (size_t)3*NBKT*BCAP;
  unsigned short* e_slot = (unsigned short*)(pn_part + (size_t)3*NBKT*BCAP);
  unsigned short* xb     = e_slot + (size_t)3*E_*CAPE_;   // 60001 rows (last = zero row)
  unsigned short* Kb  = (unsigned short*)U;
  unsigned short* Vtg = Kb + (size_t)H_*NK_*16;

  // ---- zero bin counters via graph memset node (frees prep/binA dependency) ----
  hipMemsetAsync(gcnt_e, 0, 4096, stream);

  // ---- merged prep + binA (independent; overlap in one launch) ----
  Ptr3f xs = {{f32(0), f32(1), f32(2)}};
  prep_binA<<<BINA_B + PB_TOT, 256, 0, stream>>>(xs, xb, f32(12), f32(14), bfB, m_buf,
                                   f32(3), f32(10), f32(11), bfQ, f32(20), f32(21), e2buf,
                                   nodes, edges, pe_part, pn_part, gcnt_e, gcnt_n);

  // ---- binB e-side ----
  binB_e<<<dim3(NBKT, 3), 256, 0, stream>>>(pe_part, gcnt_e, cnt_all, e_slot);

  // ---- binB n-side overlapped with edge gather ----
  egather_binbn<<<NBB + EGB, 256, 0, stream>>>(xb, cnt_all, e_slot, m_mean,
                                               pn_part, gcnt_n, cnt_all, n_slot);

  // ---- theta GEMM + node gather ----
  GemmB g;
  for (int mod=0; mod<3; mod++){
    g.A[mod] = m_mean + (size_t)mod*E_*D_;
    g.W[mod] = f32(4 + 2*mod);
    g.C[mod] = m_buf + (size_t)mod*E_*D_;
  }
  gemm_b<<<dim3((E_+63)/64, 3), 256, 0, stream>>>(g, E_);
  Ptr3f biases = {{f32(5), f32(7), f32(9)}};
  n_gather_g<<<dim3(N_/16, 3), 256, 0, stream>>>(m_buf, cnt_all, n_slot, biases, relbf);

  // ---- MHA ----
  gemm_kv_mfma<<<KVBLK, 256, 0, stream>>>(relbf, bfB, f32(13), f32(15), Kb, Vtg);
  flash3<<<dim3(NCH3, H_), 256, 0, stream>>>(Kb, Vtg, bfQ, fpart);
  merge_oproj_e1<<<C_, 512, 0, stream>>>(fpart, f32(16), f32(17), f32(18), f32(19),
                                         attentive, e1buf);

  // ---- fused tail + scores ----
  tail_scores<<<(NENT_+255)/256, 256, 0, stream>>>(attentive, f32(3), f32(20), f32(21),
                                                   e1buf, e2buf, f32(22), f32(23), (float*)d_out);
}